// Round 6
// baseline (1217.878 us; speedup 1.0000x reference)
//
#include <hip/hip_runtime.h>
#include <stdint.h>

typedef unsigned short u16;

#define S_   7
#define B_   4096
#define D_   1024
#define E_   128
#define H_   512
#define V_   200
#define D0_  1152   // D+E
#define KX0  1664   // D0+H  (xcat width: [x | h0])
#define KX1  1024   // 2H    (x1cat width: [x1 | h1])
#define G4H  2048   // 4H

typedef __bf16 bf16x8 __attribute__((ext_vector_type(8)));
typedef float  f32x4  __attribute__((ext_vector_type(4)));
typedef u16    u16x8  __attribute__((ext_vector_type(8)));

__device__ __forceinline__ u16 f2bf(float f) {
  union { float f; uint32_t u; } v; v.f = f;
  uint32_t r = v.u + 0x7fffu + ((v.u >> 16) & 1u);   // RNE
  return (u16)(r >> 16);
}
__device__ __forceinline__ float bf2f(u16 b) {
  union { uint32_t u; float f; } v; v.u = ((uint32_t)b) << 16;
  return v.f;
}
__device__ __forceinline__ float sigmoidf_(float x) { return 1.0f / (1.0f + __expf(-x)); }
__device__ __forceinline__ float tanhf_(float x) {
  float t = __expf(-2.f * fabsf(x));
  return copysignf((1.f - t) / (1.f + t), x);
}

__device__ __forceinline__ void glds16(const u16* g, u16* l) {
  __builtin_amdgcn_global_load_lds(
      (const __attribute__((address_space(1))) uint32_t*)g,
      (__attribute__((address_space(3))) uint32_t*)l, 16, 0, 0);
}

__device__ __forceinline__ void cvt8(const float* src, u16x8* dst) {
  const float4* p = (const float4*)src;
  float4 x = p[0], y = p[1];
  u16x8 o;
  o[0]=f2bf(x.x); o[1]=f2bf(x.y); o[2]=f2bf(x.z); o[3]=f2bf(x.w);
  o[4]=f2bf(y.x); o[5]=f2bf(y.y); o[6]=f2bf(y.z); o[7]=f2bf(y.w);
  *dst = o;
}

// ---------- gates pack, 4-way ILP: [Wih|Whh] concat-K, gate-interleaved rows --
template<int KA, int KB, int KK>
__global__ void pack_gates4(const float* __restrict__ Wih, const float* __restrict__ Whh,
                            u16* __restrict__ dst) {
  const int NG = KK / 8;
  const int stride = gridDim.x * 256;
  int idx = blockIdx.x * 256 + threadIdx.x;
  long daddr[4]; const float* saddr[4];
  #pragma unroll
  for (int u = 0; u < 4; ++u) {
    int i = idx + u * stride;
    int sr = i / NG, kg = i - sr * NG;
    int k8 = kg * 8;
    long s = sr >> 11;
    int  r = sr & 2047;
    int  g = r >> 9, j = r & 511;
    long drow = (s << 11) + ((j >> 4) * 64 + g * 16 + (j & 15));
    daddr[u] = drow * KK + k8;
    saddr[u] = (k8 + 8 <= KA) ? (Wih + (long)sr * KA + k8)
                              : (Whh + (long)sr * KB + (k8 - KA));
  }
  float v[4][8];
  #pragma unroll
  for (int u = 0; u < 4; ++u) {
    const float4* p = (const float4*)saddr[u];
    float4 x = p[0], y = p[1];
    v[u][0]=x.x; v[u][1]=x.y; v[u][2]=x.z; v[u][3]=x.w;
    v[u][4]=y.x; v[u][5]=y.y; v[u][6]=y.z; v[u][7]=y.w;
  }
  #pragma unroll
  for (int u = 0; u < 4; ++u) {
    u16x8 o;
    #pragma unroll
    for (int q = 0; q < 8; ++q) o[q] = f2bf(v[u][q]);
    *(u16x8*)&dst[daddr[u]] = o;
  }
}

// ---------- highway/linear pack, 4-way ILP: [hw16|lin16] interleave ----------
template<int KS>
__global__ void pack_hl4(const float* __restrict__ src, u16* __restrict__ dst, int off16) {
  const int NG = KX0 / 8;   // 208
  const int stride = gridDim.x * 256;
  int idx = blockIdx.x * 256 + threadIdx.x;
  #pragma unroll
  for (int u = 0; u < 4; ++u) {
    int i = idx + u * stride;
    int sj = i / NG, kg = i - sj * NG;
    int k8 = kg * 8;
    long s = sj >> 9;
    int  j = sj & 511;
    long drow = (s << 10) + ((j >> 4) * 32 + off16 + (j & 15));
    u16x8 o;
    if (k8 + 8 <= KS) {
      cvt8(src + (long)sj * KS + k8, &o);
    } else {
      #pragma unroll
      for (int q = 0; q < 8; ++q) o[q] = 0;
    }
    *(u16x8*)&dst[drow * KX0 + k8] = o;
  }
}

// ---------- pred pack, 4-way ILP (identity rows, zero pad past D_) -----------
__global__ void pack_pred4(const float* __restrict__ pred, u16* __restrict__ dst) {
  const int NG = KX0 / 8;   // 208
  const int stride = gridDim.x * 256;
  int idx = blockIdx.x * 256 + threadIdx.x;
  #pragma unroll
  for (int u = 0; u < 4; ++u) {
    int i = idx + u * stride;
    int row = i / NG, kg = i - row * NG;
    int k8 = kg * 8;
    u16x8 o;
    if (k8 + 8 <= D_) {
      cvt8(pred + (long)row * D_ + k8, &o);
    } else {
      #pragma unroll
      for (int q = 0; q < 8; ++q) o[q] = 0;
    }
    *(u16x8*)&dst[(long)row * KX0 + k8] = o;
  }
}

__global__ void bias_sum(const float* __restrict__ a, const float* __restrict__ b,
                         float* __restrict__ o, int n) {
  int i = blockIdx.x * 256 + threadIdx.x;
  if (i < n) o[i] = a[i] + b[i];
}

__global__ void zero_f(float* __restrict__ p, int n) {
  for (int i = blockIdx.x * 256 + threadIdx.x; i < n; i += gridDim.x * 256) p[i] = 0.f;
}
__global__ void zero_u16k(u16* __restrict__ p, int n) {
  for (int i = blockIdx.x * 256 + threadIdx.x; i < n; i += gridDim.x * 256) p[i] = 0;
}

// ---------------- per-slot embedding gather into xcat[:,1024:1152] -----------
__global__ void gather_emb(const float* __restrict__ emb_s, const int* __restrict__ idx_s,
                           u16* __restrict__ xcat) {
  long b = blockIdx.x;
  int e = threadIdx.x;
  int ix = idx_s[b];
  xcat[b * KX0 + D_ + e] = f2bf(emb_s[(long)ix * E_ + e]);
}

// ---------------- fused bf16 MFMA GEMM + epilogue ----------------------------
// 128x128 tile, BK=64.  A fragments loaded DIRECTLY global->VGPR (A panel is
// L1/L2-hot: 16 col-blocks + paired waves share it) with 1-step register
// ping-pong prefetch; only W (the HBM stream) goes through LDS via
// global_load_lds, double-buffered, XOR-swizzled.  LDS traffic per CU-iter
// halves vs staging both operands (the measured wall).  __syncthreads paces
// the W ring (prefetch lead = 1 full iter >> HBM latency).  XCD-chunked grid.
// MODE 0: LSTM cell epilogue (gate-interleaved weights; acc[m][0..3]=i,f,g,o).
// MODE 1: highway epilogue ([hw16|lin16] weights; reads h0 bf16 from xcat).
template<int MODE>
__global__ __launch_bounds__(256)
void gemm_fused(const u16* __restrict__ A, int lda,
                const u16* __restrict__ W, int ldw,
                int K, int ntn, int cpx,
                const float* __restrict__ bsum,   // MODE0: [2048]; MODE1: hwb [512]
                float* __restrict__ cbuf,         // MODE0 only
                u16* __restrict__ hdst, int hld, int hoff,
                float* __restrict__ hf32,         // MODE0 optional f32 h out (or null)
                const u16* __restrict__ xcat0) {  // MODE1: h0 bf16 source
  __shared__ __align__(16) u16 lW[2 * 8192];     // W double buffer, 32 KiB
  const int tid  = threadIdx.x;
  const int lane = tid & 63;
  const int wave = tid >> 6;
  const int p    = blockIdx.x;
  const int bid  = (p & 7) * cpx + (p >> 3);     // XCD-chunked remap (grid%8==0)
  const int tn = bid % ntn;
  const int tm = bid / ntn;
  const long row0 = (long)tm * 128;
  const long col0 = (long)tn * 128;
  const int wm = (wave >> 1) * 64;
  const int wn = (wave & 1) * 64;
  const int fr = lane & 15;
  const int fk = (lane >> 4) * 8;
  const int wr = wave * 32;

  // W staging: wave covers rows [wr, wr+32), 4 issues of 8 rows; source col
  // pre-swizzled so linear LDS dest + XOR'd read return the right element.
  const int srow = wr + (lane >> 3);
  const int scol = ((lane & 7) ^ ((lane >> 3) & 7)) * 8;
  const u16* gw = W + (col0 + srow) * (long)ldw + scol;
  const int dst0 = wr * 64 + lane * 8;

  // A fragment base: lane owns row (row0 + wm + fr) within its wave's 64-row slab
  const u16* Ag = A + (row0 + wm + fr) * (long)lda;

  // W fragment read offsets, XOR-swizzled within the 64-col row
  int woff[4];
  #pragma unroll
  for (int n = 0; n < 4; ++n) woff[n] = (wn + n * 16 + fr) * 64;
  const int swz = (fr & 7) << 3;
  const int kk0 = (0 + fk) ^ swz;
  const int kk1 = (32 + fk) ^ swz;

  f32x4 acc[4][4] = {};
  const int nt = K >> 6;    // always even for our K (26, 26, 16)

  auto stW = [&](int t, int b) {
    const u16* g = gw + ((long)t << 6);
    u16* d = lW + b * 8192 + dst0;
    #pragma unroll
    for (int i = 0; i < 4; ++i) glds16(g + (long)(i * 8) * ldw, d + i * 512);
  };
  auto loadA = [&](int t, bf16x8* a0, bf16x8* a1) {
    const long k0 = (long)t << 6;
    #pragma unroll
    for (int m = 0; m < 4; ++m) {
      a0[m] = *(const bf16x8*)&Ag[(long)(m * 16) * lda + k0 + fk];
      a1[m] = *(const bf16x8*)&Ag[(long)(m * 16) * lda + k0 + 32 + fk];
    }
  };
  auto compute = [&](const bf16x8* a0, const bf16x8* a1, const u16* Wb) {
    bf16x8 wf0[4], wf1[4];
    #pragma unroll
    for (int n = 0; n < 4; ++n) wf0[n] = *(const bf16x8*)&Wb[woff[n] + kk0];
    #pragma unroll
    for (int n = 0; n < 4; ++n) wf1[n] = *(const bf16x8*)&Wb[woff[n] + kk1];
    #pragma unroll
    for (int m = 0; m < 4; ++m)
      #pragma unroll
      for (int n = 0; n < 4; ++n)
        acc[m][n] = __builtin_amdgcn_mfma_f32_16x16x32_bf16(a0[m], wf0[n], acc[m][n], 0, 0, 0);
    #pragma unroll
    for (int m = 0; m < 4; ++m)
      #pragma unroll
      for (int n = 0; n < 4; ++n)
        acc[m][n] = __builtin_amdgcn_mfma_f32_16x16x32_bf16(a1[m], wf1[n], acc[m][n], 0, 0, 0);
  };

  bf16x8 afA0[4], afA1[4], afB0[4], afB1[4];

  // prologue: W(0) -> buf0, A(0) -> regs
  stW(0, 0);
  loadA(0, afA0, afA1);

  for (int t = 0; t < nt; t += 2) {
    __syncthreads();                       // W(t) DMA complete (vmcnt drain)
    stW(t + 1, 1);                         // prefetch W(t+1)
    loadA(t + 1, afB0, afB1);              // prefetch A(t+1) -> regs
    compute(afA0, afA1, lW);               // tile t from buf0
    __syncthreads();                       // W(t+1) complete; buf0 free
    if (t + 2 < nt) {
      stW(t + 2, 0);                       // prefetch W(t+2)
      loadA(t + 2, afA0, afA1);
    }
    compute(afB0, afB1, lW + 8192);        // tile t+1 from buf1
  }

  const int cr = (lane >> 4) * 4;
  const int jg = wn >> 6;   // 0 or 1

  if (MODE == 0) {
    const int j = tn * 32 + jg * 16 + fr;
    const float bi = bsum[j], bf = bsum[512 + j], bg = bsum[1024 + j], bo = bsum[1536 + j];
    #pragma unroll
    for (int m = 0; m < 4; ++m) {
      const long rbase = row0 + wm + m * 16 + cr;
      #pragma unroll
      for (int r = 0; r < 4; ++r) {
        const long ri = rbase + r;
        float gi = acc[m][0][r] + bi;
        float gf = acc[m][1][r] + bf;
        float gg = acc[m][2][r] + bg;
        float go = acc[m][3][r] + bo;
        float cv = cbuf[ri * H_ + j];
        float cn = sigmoidf_(gf) * cv + sigmoidf_(gi) * tanhf_(gg);
        float hn = sigmoidf_(go) * tanhf_(cn);
        cbuf[ri * H_ + j] = cn;
        hdst[ri * hld + hoff + j] = f2bf(hn);
        if (hf32) hf32[ri * H_ + j] = hn;
      }
    }
  } else {
    #pragma unroll
    for (int pp = 0; pp < 2; ++pp) {
      const int j = tn * 64 + jg * 32 + pp * 16 + fr;
      const float bj = bsum[j];
      #pragma unroll
      for (int m = 0; m < 4; ++m) {
        const long rbase = row0 + wm + m * 16 + cr;
        #pragma unroll
        for (int r = 0; r < 4; ++r) {
          const long ri = rbase + r;
          float gv = sigmoidf_(acc[m][2 * pp][r] + bj);
          float h0 = bf2f(xcat0[ri * KX0 + D0_ + j]);
          float x1 = gv * h0 + (1.f - gv) * acc[m][2 * pp + 1][r];
          hdst[ri * hld + hoff + j] = f2bf(x1);
        }
      }
    }
  }
}

extern "C" void kernel_launch(void* const* d_in, const int* in_sizes, int n_in,
                              void* d_out, int out_size, void* d_ws, size_t ws_size,
                              hipStream_t stream) {
  const float* pred   = (const float*)d_in[0];
  const int*   labels = (const int*)d_in[1];
  const float* emb    = (const float*)d_in[2];
  const float* Wih0   = (const float*)d_in[3];
  const float* Whh0   = (const float*)d_in[4];
  const float* bih0   = (const float*)d_in[5];
  const float* bhh0   = (const float*)d_in[6];
  const float* hwW0   = (const float*)d_in[7];
  const float* hwb0   = (const float*)d_in[8];
  const float* linW0  = (const float*)d_in[9];
  const float* Wih1   = (const float*)d_in[10];
  const float* Whh1   = (const float*)d_in[11];
  const float* bih1   = (const float*)d_in[12];
  const float* bhh1   = (const float*)d_in[13];
  float* out = (float*)d_out;

  char* ws = (char*)d_ws;
  size_t off = 0;
  auto alloc = [&](size_t bytes) {
    char* p = ws + off;
    off = (off + bytes + 255) & ~(size_t)255;
    return p;
  };
  u16* WC0   = (u16*)alloc((size_t)S_ * G4H * KX0 * 2);   // gate-interleaved [Wih0|Whh0]
  u16* WHL   = (u16*)alloc((size_t)S_ * 1024 * KX0 * 2);  // [hw16|lin16] interleave
  u16* WC1   = (u16*)alloc((size_t)S_ * G4H * KX1 * 2);   // gate-interleaved [Wih1|Whh1]
  u16* xcat  = (u16*)alloc((size_t)B_ * KX0 * 2);         // [pred|emb|h0] bf16
  u16* x1cat = (u16*)alloc((size_t)B_ * KX1 * 2);         // [x1|h1] bf16
  float* c0   = (float*)alloc((size_t)B_ * H_ * 4);
  float* c1   = (float*)alloc((size_t)B_ * H_ * 4);
  float* bs0  = (float*)alloc((size_t)S_ * G4H * 4);      // bih0+bhh0
  float* bs1  = (float*)alloc((size_t)S_ * G4H * 4);      // bih1+bhh1

  // -------- phase A: weight conversion + state init ---------------------------
  pack_gates4<D0_, H_, KX0><<<2912, 256, 0, stream>>>(Wih0, Whh0, WC0);  // 7*2048*208/1024
  pack_gates4<H_,  H_, KX1><<<1792, 256, 0, stream>>>(Wih1, Whh1, WC1);  // 7*2048*128/1024
  pack_hl4<KX0><<<728, 256, 0, stream>>>(hwW0,  WHL, 0);                 // 7*512*208/1024
  pack_hl4<D0_><<<728, 256, 0, stream>>>(linW0, WHL, 16);
  pack_pred4<<<832, 256, 0, stream>>>(pred, xcat);                       // 4096*208/1024
  bias_sum<<<(S_ * G4H + 255) / 256, 256, 0, stream>>>(bih0, bhh0, bs0, S_ * G4H);
  bias_sum<<<(S_ * G4H + 255) / 256, 256, 0, stream>>>(bih1, bhh1, bs1, S_ * G4H);
  zero_f<<<256, 256, 0, stream>>>(c0, B_ * H_);
  zero_f<<<256, 256, 0, stream>>>(c1, B_ * H_);
  zero_u16k<<<256, 256, 0, stream>>>(x1cat, B_ * KX1);

  const int g0 = (B_ / 128) * (G4H / 128);    // 512 blocks (= 2/CU, all resident)
  const int g1 = (B_ / 128) * (1024 / 128);   // 256 blocks

  // -------- sequential slot loop ----------------------------------------------
  for (int s = 0; s < S_; ++s) {
    gather_emb<<<B_, E_, 0, stream>>>(emb + (size_t)s * V_ * E_, labels + (size_t)s * B_, xcat);

    // layer-0 gates + cell (fused): [x|h0] @ WC0^T, M=4096,N=2048,K=1664
    gemm_fused<0><<<g0, 256, 0, stream>>>(
        xcat, KX0, WC0 + (size_t)s * G4H * KX0, KX0, KX0, G4H / 128, g0 / 8,
        bs0 + (size_t)s * G4H, c0, xcat, KX0, D0_, nullptr, nullptr);

    // merged highway+linear + combine (fused): N=1024,K=1664
    gemm_fused<1><<<g1, 256, 0, stream>>>(
        xcat, KX0, WHL + (size_t)s * 1024 * KX0, KX0, KX0, 1024 / 128, g1 / 8,
        hwb0 + (size_t)s * H_, nullptr, x1cat, KX1, 0, nullptr, xcat);

    // layer-1 gates + cell (fused): [x1|h1] @ WC1^T, N=2048,K=1024
    gemm_fused<0><<<g0, 256, 0, stream>>>(
        x1cat, KX1, WC1 + (size_t)s * G4H * KX1, KX1, KX1, G4H / 128, g0 / 8,
        bs1 + (size_t)s * G4H, c1, x1cat, KX1, H_, out, nullptr);
  }
}

// Round 7
// 699.541 us; speedup vs baseline: 1.7410x; 1.7410x over previous
//
#include <hip/hip_runtime.h>
#include <stdint.h>

typedef unsigned short u16;

#define S_   7
#define B_   4096
#define D_   1024
#define E_   128
#define H_   512
#define V_   200
#define D0_  1152   // D+E
#define XLD  1536   // xcat width: [pred(1024) | h0(512)] ; emb lives in EMB buffer
#define K0_  1664   // gates0 / WHL GEMM K  (pred 1024 + h0 512 + emb 128)
#define KX1  1024   // 2H    (x1cat width: [x1 | h1])
#define G4H  2048   // 4H

typedef __bf16 bf16x8 __attribute__((ext_vector_type(8)));
typedef float  f32x4  __attribute__((ext_vector_type(4)));
typedef u16    u16x8  __attribute__((ext_vector_type(8)));

__device__ __forceinline__ u16 f2bf(float f) {
  union { float f; uint32_t u; } v; v.f = f;
  uint32_t r = v.u + 0x7fffu + ((v.u >> 16) & 1u);   // RNE
  return (u16)(r >> 16);
}
__device__ __forceinline__ float bf2f(u16 b) {
  union { uint32_t u; float f; } v; v.u = ((uint32_t)b) << 16;
  return v.f;
}
__device__ __forceinline__ float sigmoidf_(float x) { return 1.0f / (1.0f + __expf(-x)); }
__device__ __forceinline__ float tanhf_(float x) {
  float t = __expf(-2.f * fabsf(x));
  return copysignf((1.f - t) / (1.f + t), x);
}

__device__ __forceinline__ void glds16(const u16* g, u16* l) {
  __builtin_amdgcn_global_load_lds(
      (const __attribute__((address_space(1))) uint32_t*)g,
      (__attribute__((address_space(3))) uint32_t*)l, 16, 0, 0);
}

__device__ __forceinline__ void cvt8(const float* src, u16x8* dst) {
  const float4* p = (const float4*)src;
  float4 x = p[0], y = p[1];
  u16x8 o;
  o[0]=f2bf(x.x); o[1]=f2bf(x.y); o[2]=f2bf(x.z); o[3]=f2bf(x.w);
  o[4]=f2bf(y.x); o[5]=f2bf(y.y); o[6]=f2bf(y.z); o[7]=f2bf(y.w);
  *dst = o;
}

// ---------- gates weight pack: contiguous 32-elem chunk per thread -----------
// dst K-order: [region1 = Wih[0..P1) | region2 = Whh[0..P2-P1) | region3 = Wih[P1..)]
// row map (per slot): src row r = g*512+j -> dst row (j>>4)*64 + g*16 + (j&15)
template<int KK, int P1, int P2, int KA, int KB>
__global__ void pack_gw(const float* __restrict__ Wih, const float* __restrict__ Whh,
                        u16* __restrict__ dst) {
  const int CH = KK / 32;
  int i = blockIdx.x * 256 + threadIdx.x;
  int sr = i / CH, c = i - sr * CH;
  int k = c * 32;
  long s = sr >> 11;
  int  r = sr & 2047;
  int  g = r >> 9, j = r & 511;
  long drow = (s << 11) + ((j >> 4) * 64 + g * 16 + (j & 15));
  const float* src = (k < P1) ? Wih + (long)sr * KA + k
                   : (k < P2) ? Whh + (long)sr * KB + (k - P1)
                              : Wih + (long)sr * KA + P1 + (k - P2);
  u16* d = dst + drow * KK + k;
  #pragma unroll
  for (int q = 0; q < 4; ++q) {
    u16x8 o; cvt8(src + q * 8, &o);
    *(u16x8*)(d + q * 8) = o;
  }
}

// ---------- highway/linear pack: [hw16|lin16] N-interleave, K-order remap ----
// dst K: [0,1024) = src x-pred cols; [1024,1536) = h cols (hw: src 1152+, lin: 0);
// [1536,1664) = x-emb cols (src 1024+).
template<int KS, bool Z2>
__global__ void pack_hw(const float* __restrict__ src, u16* __restrict__ dst, int off16) {
  const int CH = K0_ / 32;   // 52
  int i = blockIdx.x * 256 + threadIdx.x;
  int sj = i / CH, c = i - sj * CH;
  int k = c * 32;
  long s = sj >> 9;
  int  j = sj & 511;
  long drow = (s << 10) + ((j >> 4) * 32 + off16 + (j & 15));
  u16* d = dst + drow * K0_ + k;
  if (k >= 1024 && k < 1536 && Z2) {
    u16x8 z = {};
    #pragma unroll
    for (int q = 0; q < 4; ++q) *(u16x8*)(d + q * 8) = z;
    return;
  }
  const float* sp = (k < 1024) ? src + (long)sj * KS + k
                  : (k < 1536) ? src + (long)sj * KS + 1152 + (k - 1024)
                               : src + (long)sj * KS + 1024 + (k - 1536);
  #pragma unroll
  for (int q = 0; q < 4; ++q) {
    u16x8 o; cvt8(sp + q * 8, &o);
    *(u16x8*)(d + q * 8) = o;
  }
}

// ---------- pred pack into xcat[:,0..1024), zeros in h0 region [1024,1536) ---
__global__ void pack_predz(const float* __restrict__ pred, u16* __restrict__ dst) {
  const int CH = XLD / 32;   // 48
  int i = blockIdx.x * 256 + threadIdx.x;
  int row = i / CH, c = i - row * CH;
  int k = c * 32;
  u16* d = dst + (long)row * XLD + k;
  if (k < 1024) {
    const float* sp = pred + (long)row * D_ + k;
    #pragma unroll
    for (int q = 0; q < 4; ++q) {
      u16x8 o; cvt8(sp + q * 8, &o);
      *(u16x8*)(d + q * 8) = o;
    }
  } else {
    u16x8 z = {};
    #pragma unroll
    for (int q = 0; q < 4; ++q) *(u16x8*)(d + q * 8) = z;
  }
}

// ---------- pre-gather ALL slots' embeddings: EMB[s][b][e] bf16 --------------
__global__ void xgather(const float* __restrict__ emb, const int* __restrict__ labels,
                        u16* __restrict__ EMB) {
  int b = blockIdx.x;
  int e = threadIdx.x;
  #pragma unroll
  for (int s = 0; s < S_; ++s) {
    int ix = labels[s * B_ + b];
    EMB[((long)(s * B_ + b)) * E_ + e] = f2bf(emb[((long)(s * V_ + ix)) * E_ + e]);
  }
}

__global__ void bias_sum(const float* __restrict__ a, const float* __restrict__ b,
                         float* __restrict__ o, int n) {
  int i = blockIdx.x * 256 + threadIdx.x;
  if (i < n) o[i] = a[i] + b[i];
}
__global__ void zero_f(float* __restrict__ p, int n) {
  for (int i = blockIdx.x * 256 + threadIdx.x; i < n; i += gridDim.x * 256) p[i] = 0.f;
}
__global__ void zero_u16k(u16* __restrict__ p, int n) {
  for (int i = blockIdx.x * 256 + threadIdx.x; i < n; i += gridDim.x * 256) p[i] = 0;
}

// ---------------- fused bf16 MFMA GEMM + epilogue ----------------------------
// Round-4 structure: 128x128 tile, BK=64, A+W both via global_load_lds into
// double-buffered LDS (64 KiB), prefetch-tile-(t+1)-then-compute-t, syncthreads
// pacing, XOR-swizzled staging (pre-swizzled global source + swizzled ds_read),
// XCD-chunked blockIdx. 4 waves (2x2 of 64x64), 16x16x32 MFMA.
// A K-tiles t < TS read xcat (lda); t >= TS read the per-slot EMB block (ld 128).
// MODE 0: LSTM cell epilogue (gate-interleaved W; acc[m][0..3] = i,f,g,o).
// MODE 1: highway epilogue ([hw16|lin16] W; reads h0 bf16 from xcat col 1024+).
template<int MODE>
__global__ __launch_bounds__(256)
void gemm_fused(const u16* __restrict__ A, int lda,
                const u16* __restrict__ EMBs,   // per-slot emb block or nullptr
                const u16* __restrict__ W, int ldw,
                int K, int TS, int ntn, int cpx,
                const float* __restrict__ bsum,   // MODE0: [2048]; MODE1: hwb [512]
                float* __restrict__ cbuf,         // MODE0 only
                u16* __restrict__ hdst, int hld, int hoff,
                float* __restrict__ hf32,         // MODE0 optional f32 h out (or null)
                const u16* __restrict__ xcat0) {  // MODE1: h0 bf16 source
  __shared__ __align__(16) u16 lds[4 * 8192];   // A buf0/1, W buf0/1 -> 64 KiB
  u16* lA = lds;
  u16* lW = lds + 2 * 8192;
  const int tid  = threadIdx.x;
  const int lane = tid & 63;
  const int wave = tid >> 6;
  const int p    = blockIdx.x;
  const int bid  = (p & 7) * cpx + (p >> 3);     // XCD-chunked remap (grid%8==0)
  const int tn = bid % ntn;
  const int tm = bid / ntn;
  const long row0 = (long)tm * 128;
  const long col0 = (long)tn * 128;
  const int wm = (wave >> 1) * 64;
  const int wn = (wave & 1) * 64;
  const int fr = lane & 15;
  const int fk = (lane >> 4) * 8;
  const int wr = wave * 32;

  // staging: wave covers rows [wr, wr+32), 4 issues of 8 rows; source col
  // pre-swizzled so linear LDS dest + XOR'd read return the right element.
  const int srow = wr + (lane >> 3);
  const int scol = ((lane & 7) ^ ((lane >> 3) & 7)) * 8;
  const u16* ga = A + (row0 + srow) * (long)lda + scol;
  const u16* ge = EMBs ? (EMBs + (row0 + srow) * (long)E_ + scol) : nullptr;
  const u16* gw = W + (col0 + srow) * (long)ldw + scol;
  const int dst0 = wr * 64 + lane * 8;

  auto stage = [&](int t, int b) {
    const u16* gb; long ld;
    if (t < TS) { gb = ga + ((long)t << 6);        ld = lda; }
    else        { gb = ge + ((long)(t - TS) << 6); ld = E_;  }
    const u16* gww = gw + ((long)t << 6);
    u16* dA = lA + b * 8192 + dst0;
    u16* dW = lW + b * 8192 + dst0;
    #pragma unroll
    for (int i = 0; i < 4; ++i) {
      glds16(gb  + (long)(i * 8) * ld,  dA + i * 512);
      glds16(gww + (long)(i * 8) * ldw, dW + i * 512);
    }
  };

  // fragment read offsets (elements), XOR-swizzled within the 64-col row
  int aoff[4], woff[4];
  #pragma unroll
  for (int m = 0; m < 4; ++m) aoff[m] = (wm + m * 16 + fr) * 64;
  #pragma unroll
  for (int n = 0; n < 4; ++n) woff[n] = (wn + n * 16 + fr) * 64;
  const int swz = (fr & 7) << 3;
  const int kk0 = (0 + fk) ^ swz;
  const int kk1 = (32 + fk) ^ swz;

  f32x4 acc[4][4] = {};
  const int nt = K >> 6;

  stage(0, 0);

  for (int t = 0; t < nt; ++t) {
    __syncthreads();                  // tile t DMA complete in buf (t&1)
    if (t + 1 < nt) stage(t + 1, (t + 1) & 1);
    const u16* Ab = lA + (t & 1) * 8192;
    const u16* Wb = lW + (t & 1) * 8192;
    bf16x8 af0[4], wf0[4], af1[4], wf1[4];
    #pragma unroll
    for (int m = 0; m < 4; ++m) af0[m] = *(const bf16x8*)&Ab[aoff[m] + kk0];
    #pragma unroll
    for (int n = 0; n < 4; ++n) wf0[n] = *(const bf16x8*)&Wb[woff[n] + kk0];
    #pragma unroll
    for (int m = 0; m < 4; ++m) af1[m] = *(const bf16x8*)&Ab[aoff[m] + kk1];
    #pragma unroll
    for (int n = 0; n < 4; ++n) wf1[n] = *(const bf16x8*)&Wb[woff[n] + kk1];
    #pragma unroll
    for (int m = 0; m < 4; ++m)
      #pragma unroll
      for (int n = 0; n < 4; ++n)
        acc[m][n] = __builtin_amdgcn_mfma_f32_16x16x32_bf16(af0[m], wf0[n], acc[m][n], 0, 0, 0);
    #pragma unroll
    for (int m = 0; m < 4; ++m)
      #pragma unroll
      for (int n = 0; n < 4; ++n)
        acc[m][n] = __builtin_amdgcn_mfma_f32_16x16x32_bf16(af1[m], wf1[n], acc[m][n], 0, 0, 0);
  }

  const int cr = (lane >> 4) * 4;
  const int jg = wn >> 6;   // 0 or 1

  if (MODE == 0) {
    const int j = tn * 32 + jg * 16 + fr;
    const float bi = bsum[j], bf = bsum[512 + j], bg = bsum[1024 + j], bo = bsum[1536 + j];
    #pragma unroll
    for (int m = 0; m < 4; ++m) {
      const long rbase = row0 + wm + m * 16 + cr;
      #pragma unroll
      for (int r = 0; r < 4; ++r) {
        const long ri = rbase + r;
        float gi = acc[m][0][r] + bi;
        float gf = acc[m][1][r] + bf;
        float gg = acc[m][2][r] + bg;
        float go = acc[m][3][r] + bo;
        float cv = cbuf[ri * H_ + j];
        float cn = sigmoidf_(gf) * cv + sigmoidf_(gi) * tanhf_(gg);
        float hn = sigmoidf_(go) * tanhf_(cn);
        cbuf[ri * H_ + j] = cn;
        hdst[ri * hld + hoff + j] = f2bf(hn);
        if (hf32) hf32[ri * H_ + j] = hn;
      }
    }
  } else {
    #pragma unroll
    for (int pp = 0; pp < 2; ++pp) {
      const int j = tn * 64 + jg * 32 + pp * 16 + fr;
      const float bj = bsum[j];
      #pragma unroll
      for (int m = 0; m < 4; ++m) {
        const long rbase = row0 + wm + m * 16 + cr;
        #pragma unroll
        for (int r = 0; r < 4; ++r) {
          const long ri = rbase + r;
          float gv = sigmoidf_(acc[m][2 * pp][r] + bj);
          float h0 = bf2f(xcat0[ri * XLD + 1024 + j]);
          float x1 = gv * h0 + (1.f - gv) * acc[m][2 * pp + 1][r];
          hdst[ri * hld + hoff + j] = f2bf(x1);
        }
      }
    }
  }
}

extern "C" void kernel_launch(void* const* d_in, const int* in_sizes, int n_in,
                              void* d_out, int out_size, void* d_ws, size_t ws_size,
                              hipStream_t stream) {
  const float* pred   = (const float*)d_in[0];
  const int*   labels = (const int*)d_in[1];
  const float* emb    = (const float*)d_in[2];
  const float* Wih0   = (const float*)d_in[3];
  const float* Whh0   = (const float*)d_in[4];
  const float* bih0   = (const float*)d_in[5];
  const float* bhh0   = (const float*)d_in[6];
  const float* hwW0   = (const float*)d_in[7];
  const float* hwb0   = (const float*)d_in[8];
  const float* linW0  = (const float*)d_in[9];
  const float* Wih1   = (const float*)d_in[10];
  const float* Whh1   = (const float*)d_in[11];
  const float* bih1   = (const float*)d_in[12];
  const float* bhh1   = (const float*)d_in[13];
  float* out = (float*)d_out;

  char* ws = (char*)d_ws;
  size_t off = 0;
  auto alloc = [&](size_t bytes) {
    char* p = ws + off;
    off = (off + bytes + 255) & ~(size_t)255;
    return p;
  };
  u16* WC0   = (u16*)alloc((size_t)S_ * G4H * K0_ * 2);   // gate-ilv [Wih0p|Whh0|Wih0e]
  u16* WHL   = (u16*)alloc((size_t)S_ * 1024 * K0_ * 2);  // [hw16|lin16] interleave
  u16* WC1   = (u16*)alloc((size_t)S_ * G4H * KX1 * 2);   // gate-ilv [Wih1|Whh1]
  u16* xcat  = (u16*)alloc((size_t)B_ * XLD * 2);         // [pred|h0] bf16
  u16* EMB   = (u16*)alloc((size_t)S_ * B_ * E_ * 2);     // pre-gathered embeddings
  u16* x1cat = (u16*)alloc((size_t)B_ * KX1 * 2);         // [x1|h1] bf16
  float* c0   = (float*)alloc((size_t)B_ * H_ * 4);
  float* c1   = (float*)alloc((size_t)B_ * H_ * 4);
  float* bs0  = (float*)alloc((size_t)S_ * G4H * 4);      // bih0+bhh0
  float* bs1  = (float*)alloc((size_t)S_ * G4H * 4);      // bih1+bhh1

  // -------- phase A: weight conversion + state init (exact grids) -------------
  pack_gw<K0_, 1024, 1536, D0_, H_><<<2912, 256, 0, stream>>>(Wih0, Whh0, WC0);  // 14336*52/256
  pack_gw<KX1,  512, 1024, H_,  H_><<<1792, 256, 0, stream>>>(Wih1, Whh1, WC1);  // 14336*32/256
  pack_hw<K0_, false><<<728, 256, 0, stream>>>(hwW0,  WHL, 0);                   // 3584*52/256
  pack_hw<D0_, true ><<<728, 256, 0, stream>>>(linW0, WHL, 16);
  pack_predz<<<768, 256, 0, stream>>>(pred, xcat);                               // 4096*48/256
  xgather<<<B_, E_, 0, stream>>>(emb, labels, EMB);
  bias_sum<<<(S_ * G4H + 255) / 256, 256, 0, stream>>>(bih0, bhh0, bs0, S_ * G4H);
  bias_sum<<<(S_ * G4H + 255) / 256, 256, 0, stream>>>(bih1, bhh1, bs1, S_ * G4H);
  zero_f<<<256, 256, 0, stream>>>(c0, B_ * H_);
  zero_f<<<256, 256, 0, stream>>>(c1, B_ * H_);
  zero_u16k<<<256, 256, 0, stream>>>(x1cat, B_ * KX1);

  const int g0 = (B_ / 128) * (G4H / 128);    // 512 blocks (2/CU, all resident)
  const int g1 = (B_ / 128) * (1024 / 128);   // 256 blocks

  // -------- sequential slot loop ----------------------------------------------
  for (int s = 0; s < S_; ++s) {
    const u16* EMBs = EMB + (size_t)s * B_ * E_;

    // layer-0 gates + cell (fused): [pred|h0|emb_s] @ WC0^T, M=4096,N=2048,K=1664
    gemm_fused<0><<<g0, 256, 0, stream>>>(
        xcat, XLD, EMBs, WC0 + (size_t)s * G4H * K0_, K0_, K0_, 24, G4H / 128, g0 / 8,
        bs0 + (size_t)s * G4H, c0, xcat, XLD, 1024, nullptr, nullptr);

    // merged highway+linear + combine (fused): N=1024,K=1664
    gemm_fused<1><<<g1, 256, 0, stream>>>(
        xcat, XLD, EMBs, WHL + (size_t)s * 1024 * K0_, K0_, K0_, 24, 1024 / 128, g1 / 8,
        hwb0 + (size_t)s * H_, nullptr, x1cat, KX1, 0, nullptr, xcat);

    // layer-1 gates + cell (fused): [x1|h1] @ WC1^T, N=2048,K=1024
    gemm_fused<0><<<g0, 256, 0, stream>>>(
        x1cat, KX1, nullptr, WC1 + (size_t)s * G4H * KX1, KX1, KX1, 16, G4H / 128, g0 / 8,
        bs1 + (size_t)s * G4H, c1, x1cat, KX1, H_, out, nullptr);
  }
}

// Round 8
// 660.031 us; speedup vs baseline: 1.8452x; 1.0599x over previous
//
#include <hip/hip_runtime.h>
#include <stdint.h>

typedef unsigned short u16;

#define S_   7
#define B_   4096
#define D_   1024
#define E_   128
#define H_   512
#define V_   200
#define D0_  1152   // D+E
#define K0_  1664   // layer-0 GEMM K: pred 1024 + h0 512 + emb 128
#define KX1  1024   // layer-1 GEMM K: x1 512 + h1 512
#define G4H  2048   // 4H
#define XW   2048   // xcat width: [pred(1024) | h0_a(512) | h0_b(512)]
#define X1W  2048   // x1cat width: [x1_a | x1_b | h1_a | h1_b]

typedef __bf16 bf16x8 __attribute__((ext_vector_type(8)));
typedef float  f32x4  __attribute__((ext_vector_type(4)));
typedef u16    u16x8  __attribute__((ext_vector_type(8)));

__device__ __forceinline__ u16 f2bf(float f) {
  union { float f; uint32_t u; } v; v.f = f;
  uint32_t r = v.u + 0x7fffu + ((v.u >> 16) & 1u);   // RNE
  return (u16)(r >> 16);
}
__device__ __forceinline__ float bf2f(u16 b) {
  union { uint32_t u; float f; } v; v.u = ((uint32_t)b) << 16;
  return v.f;
}
__device__ __forceinline__ float sigmoidf_(float x) { return 1.0f / (1.0f + __expf(-x)); }
__device__ __forceinline__ float tanhf_(float x) {
  float t = __expf(-2.f * fabsf(x));
  return copysignf((1.f - t) / (1.f + t), x);
}

__device__ __forceinline__ void glds16(const u16* g, u16* l) {
  __builtin_amdgcn_global_load_lds(
      (const __attribute__((address_space(1))) uint32_t*)g,
      (__attribute__((address_space(3))) uint32_t*)l, 16, 0, 0);
}

__device__ __forceinline__ void cvt8s(const float* src, u16* dst) {
  const float4* p = (const float4*)src;
  float4 x = p[0], y = p[1];
  u16x8 o;
  o[0]=f2bf(x.x); o[1]=f2bf(x.y); o[2]=f2bf(x.z); o[3]=f2bf(x.w);
  o[4]=f2bf(y.x); o[5]=f2bf(y.y); o[6]=f2bf(y.z); o[7]=f2bf(y.w);
  *(u16x8*)dst = o;
}

// ---------- gates pack, spread-ILP (lane-contiguous 16B chunks) --------------
// dst K-order: [Wih[0..P1) | Whh[0..P2-P1) | Wih[P1..P1+KK-P2)]
// row map (per slot): src row r = g*512+j -> dst row (j>>4)*64 + g*16 + (j&15)
template<int KK, int P1, int P2, int KA, int KB>
__global__ void pack_gw4(const float* __restrict__ Wih, const float* __restrict__ Whh,
                         u16* __restrict__ dst) {
  const int NG = KK / 8;
  const int stride = gridDim.x * 256;
  int idx = blockIdx.x * 256 + threadIdx.x;
  #pragma unroll
  for (int u = 0; u < 4; ++u) {
    int i = idx + u * stride;
    int sr = i / NG, kg = i - sr * NG;
    int k8 = kg * 8;
    long s = sr >> 11;
    int  r = sr & 2047;
    int  g = r >> 9, j = r & 511;
    long drow = (s << 11) + ((j >> 4) * 64 + g * 16 + (j & 15));
    const float* sp = (k8 < P1) ? Wih + (long)sr * KA + k8
                    : (k8 < P2) ? Whh + (long)sr * KB + (k8 - P1)
                                : Wih + (long)sr * KA + P1 + (k8 - P2);
    cvt8s(sp, &dst[drow * KK + k8]);
  }
}

// ---------- highway/linear pack: [hw16|lin16] N-interleave, K-order remap ----
// dst K: [0,1024)=x-pred; [1024,1536)=h (hw: src 1152+, lin: ZERO); [1536,1664)=x-emb
template<int KS, bool Z2>
__global__ void pack_hw4(const float* __restrict__ src, u16* __restrict__ dst, int off16) {
  const int NG = K0_ / 8;   // 208
  const int stride = gridDim.x * 256;
  int idx = blockIdx.x * 256 + threadIdx.x;
  #pragma unroll
  for (int u = 0; u < 4; ++u) {
    int i = idx + u * stride;
    int sj = i / NG, kg = i - sj * NG;
    int k8 = kg * 8;
    long s = sj >> 9;
    int  j = sj & 511;
    long drow = (s << 10) + ((j >> 4) * 32 + off16 + (j & 15));
    u16* d = &dst[drow * K0_ + k8];
    if (Z2 && k8 >= 1024 && k8 < 1536) {
      u16x8 z = {};
      *(u16x8*)d = z;
    } else {
      const float* sp = (k8 < 1024) ? src + (long)sj * KS + k8
                      : (k8 < 1536) ? src + (long)sj * KS + 1152 + (k8 - 1024)
                                    : src + (long)sj * KS + 1024 + (k8 - 1536);
      cvt8s(sp, d);
    }
  }
}

// ---------- pred pack into xcat[:,0..1024), zeros in both h0 slots -----------
__global__ void pack_predz4(const float* __restrict__ pred, u16* __restrict__ dst) {
  const int NG = XW / 8;   // 256
  const int stride = gridDim.x * 256;
  int idx = blockIdx.x * 256 + threadIdx.x;
  #pragma unroll
  for (int u = 0; u < 4; ++u) {
    int i = idx + u * stride;
    int row = i / NG, kg = i - row * NG;
    int k8 = kg * 8;
    u16* d = &dst[(long)row * XW + k8];
    if (k8 < 1024) {
      cvt8s(pred + (long)row * D_ + k8, d);
    } else {
      u16x8 z = {};
      *(u16x8*)d = z;
    }
  }
}

// ---------- pre-gather ALL slots' embeddings: EMB[s][b][e] bf16 --------------
__global__ void xgather(const float* __restrict__ emb, const int* __restrict__ labels,
                        u16* __restrict__ EMB) {
  int b = blockIdx.x;
  int e = threadIdx.x;
  #pragma unroll
  for (int s = 0; s < S_; ++s) {
    int ix = labels[s * B_ + b];
    EMB[((long)(s * B_ + b)) * E_ + e] = f2bf(emb[((long)(s * V_ + ix)) * E_ + e]);
  }
}

__global__ void bias_sum(const float* __restrict__ a, const float* __restrict__ b,
                         float* __restrict__ o, int n) {
  int i = blockIdx.x * 256 + threadIdx.x;
  if (i < n) o[i] = a[i] + b[i];
}
__global__ void zero_f(float* __restrict__ p, int n) {
  for (int i = blockIdx.x * 256 + threadIdx.x; i < n; i += gridDim.x * 256) p[i] = 0.f;
}
__global__ void zero_u16k(u16* __restrict__ p, int n) {
  for (int i = blockIdx.x * 256 + threadIdx.x; i < n; i += gridDim.x * 256) p[i] = 0;
}

// ---------------- multi-role fused GEMM launch -------------------------------
// Roles A (G0_k), B (WHL_{k-1}), C (G1_{k-2}) run concurrently, selected by
// block range. Engine = round-4 structure: 128x128 tile, BK=64, A+W via
// global_load_lds, double-buffered LDS (64 KiB), prefetch-(t+1)-then-compute-t,
// syncthreads pacing, XOR-swizzled staging, per-role XCD-chunked remap.
// A-operand K-space = up to 3 regions (ptr, ld, start-tile).
// mode 0: LSTM cell epilogue (gate-interleaved W; acc[m][0..3] = i,f,g,o).
// mode 1: highway epilogue ([hw16|lin16] W; h0 read from h0src).
struct GemmP {
  const u16* r0; const u16* r1; const u16* r2;
  const u16* W;
  const float* bsum;
  float* cbuf;
  u16* hdst;
  float* hf32;
  const u16* h0src;
  int ld0, ld1, ld2, t1, t2, ldw, nt, ntn, cpx, hld, hoff, h0ld, mode;
};

__global__ __launch_bounds__(256)
void gemm_multi(GemmP pa, GemmP pb, GemmP pc, int nA, int nAB) {
  __shared__ __align__(16) u16 lds[4 * 8192];   // A buf0/1, W buf0/1
  const int b = blockIdx.x;
  GemmP P = pc; int base = nAB;
  if (b < nAB) { P = pb; base = nA; }
  if (b < nA)  { P = pa; base = 0; }
  const int bidx = b - base;

  u16* lA = lds;
  u16* lW = lds + 2 * 8192;
  const int tid  = threadIdx.x;
  const int lane = tid & 63;
  const int wave = tid >> 6;
  const int bid  = (bidx & 7) * P.cpx + (bidx >> 3);   // XCD-chunked (count%8==0)
  const int tn = bid % P.ntn;
  const int tm = bid / P.ntn;
  const long row0 = (long)tm * 128;
  const long col0 = (long)tn * 128;
  const int wm = (wave >> 1) * 64;
  const int wn = (wave & 1) * 64;
  const int fr = lane & 15;
  const int fk = (lane >> 4) * 8;
  const int wr = wave * 32;

  const int srow = wr + (lane >> 3);
  const int scol = ((lane & 7) ^ ((lane >> 3) & 7)) * 8;
  const u16* gr0 = P.r0 + (row0 + srow) * (long)P.ld0 + scol;
  const u16* gr1 = P.r1 + (row0 + srow) * (long)P.ld1 + scol;
  const u16* gr2 = P.r2 + (row0 + srow) * (long)P.ld2 + scol;
  const u16* gw  = P.W  + (col0 + srow) * (long)P.ldw + scol;
  const int dst0 = wr * 64 + lane * 8;

  auto stage = [&](int t, int buf) {
    const u16* g; long ld;
    if (t < P.t1)      { g = gr0 + (long)t * 64;            ld = P.ld0; }
    else if (t < P.t2) { g = gr1 + (long)(t - P.t1) * 64;   ld = P.ld1; }
    else               { g = gr2 + (long)(t - P.t2) * 64;   ld = P.ld2; }
    const u16* gww = gw + (long)t * 64;
    u16* dA = lA + buf * 8192 + dst0;
    u16* dW = lW + buf * 8192 + dst0;
    #pragma unroll
    for (int i = 0; i < 4; ++i) {
      glds16(g   + (long)(i * 8) * ld,    dA + i * 512);
      glds16(gww + (long)(i * 8) * P.ldw, dW + i * 512);
    }
  };

  int aoff[4], woff[4];
  #pragma unroll
  for (int m = 0; m < 4; ++m) aoff[m] = (wm + m * 16 + fr) * 64;
  #pragma unroll
  for (int n = 0; n < 4; ++n) woff[n] = (wn + n * 16 + fr) * 64;
  const int swz = (fr & 7) << 3;
  const int kk0 = (0 + fk) ^ swz;
  const int kk1 = (32 + fk) ^ swz;

  f32x4 acc[4][4] = {};
  const int nt = P.nt;

  stage(0, 0);

  for (int t = 0; t < nt; ++t) {
    __syncthreads();                  // tile t DMA complete in buf (t&1)
    if (t + 1 < nt) stage(t + 1, (t + 1) & 1);
    const u16* Ab = lA + (t & 1) * 8192;
    const u16* Wb = lW + (t & 1) * 8192;
    bf16x8 af0[4], wf0[4], af1[4], wf1[4];
    #pragma unroll
    for (int m = 0; m < 4; ++m) af0[m] = *(const bf16x8*)&Ab[aoff[m] + kk0];
    #pragma unroll
    for (int n = 0; n < 4; ++n) wf0[n] = *(const bf16x8*)&Wb[woff[n] + kk0];
    #pragma unroll
    for (int m = 0; m < 4; ++m) af1[m] = *(const bf16x8*)&Ab[aoff[m] + kk1];
    #pragma unroll
    for (int n = 0; n < 4; ++n) wf1[n] = *(const bf16x8*)&Wb[woff[n] + kk1];
    #pragma unroll
    for (int m = 0; m < 4; ++m)
      #pragma unroll
      for (int n = 0; n < 4; ++n)
        acc[m][n] = __builtin_amdgcn_mfma_f32_16x16x32_bf16(af0[m], wf0[n], acc[m][n], 0, 0, 0);
    #pragma unroll
    for (int m = 0; m < 4; ++m)
      #pragma unroll
      for (int n = 0; n < 4; ++n)
        acc[m][n] = __builtin_amdgcn_mfma_f32_16x16x32_bf16(af1[m], wf1[n], acc[m][n], 0, 0, 0);
  }

  const int cr = (lane >> 4) * 4;
  const int jg = wn >> 6;   // 0 or 1

  if (P.mode == 0) {
    const int j = tn * 32 + jg * 16 + fr;
    const float bi = P.bsum[j], bf = P.bsum[512 + j];
    const float bg = P.bsum[1024 + j], bo = P.bsum[1536 + j];
    #pragma unroll
    for (int m = 0; m < 4; ++m) {
      const long rbase = row0 + wm + m * 16 + cr;
      #pragma unroll
      for (int r = 0; r < 4; ++r) {
        const long ri = rbase + r;
        float gi = acc[m][0][r] + bi;
        float gf = acc[m][1][r] + bf;
        float gg = acc[m][2][r] + bg;
        float go = acc[m][3][r] + bo;
        float cv = P.cbuf[ri * H_ + j];
        float cn = sigmoidf_(gf) * cv + sigmoidf_(gi) * tanhf_(gg);
        float hn = sigmoidf_(go) * tanhf_(cn);
        P.cbuf[ri * H_ + j] = cn;
        P.hdst[ri * P.hld + P.hoff + j] = f2bf(hn);
        if (P.hf32) P.hf32[ri * H_ + j] = hn;
      }
    }
  } else {
    #pragma unroll
    for (int pp = 0; pp < 2; ++pp) {
      const int j = tn * 64 + jg * 32 + pp * 16 + fr;
      const float bj = P.bsum[j];
      #pragma unroll
      for (int m = 0; m < 4; ++m) {
        const long rbase = row0 + wm + m * 16 + cr;
        #pragma unroll
        for (int r = 0; r < 4; ++r) {
          const long ri = rbase + r;
          float gv = sigmoidf_(acc[m][2 * pp][r] + bj);
          float h0 = bf2f(P.h0src[ri * (long)P.h0ld + j]);
          float x1 = gv * h0 + (1.f - gv) * acc[m][2 * pp + 1][r];
          P.hdst[ri * P.hld + P.hoff + j] = f2bf(x1);
        }
      }
    }
  }
}

extern "C" void kernel_launch(void* const* d_in, const int* in_sizes, int n_in,
                              void* d_out, int out_size, void* d_ws, size_t ws_size,
                              hipStream_t stream) {
  const float* pred   = (const float*)d_in[0];
  const int*   labels = (const int*)d_in[1];
  const float* emb    = (const float*)d_in[2];
  const float* Wih0   = (const float*)d_in[3];
  const float* Whh0   = (const float*)d_in[4];
  const float* bih0   = (const float*)d_in[5];
  const float* bhh0   = (const float*)d_in[6];
  const float* hwW0   = (const float*)d_in[7];
  const float* hwb0   = (const float*)d_in[8];
  const float* linW0  = (const float*)d_in[9];
  const float* Wih1   = (const float*)d_in[10];
  const float* Whh1   = (const float*)d_in[11];
  const float* bih1   = (const float*)d_in[12];
  const float* bhh1   = (const float*)d_in[13];
  float* out = (float*)d_out;

  char* ws = (char*)d_ws;
  size_t off = 0;
  auto alloc = [&](size_t bytes) {
    char* p = ws + off;
    off = (off + bytes + 255) & ~(size_t)255;
    return p;
  };
  u16* WC0   = (u16*)alloc((size_t)S_ * G4H * K0_ * 2);   // gate-ilv [Wp|Wh|We]
  u16* WHLw  = (u16*)alloc((size_t)S_ * 1024 * K0_ * 2);  // [hw16|lin16]
  u16* WC1   = (u16*)alloc((size_t)S_ * G4H * KX1 * 2);   // gate-ilv [Wih1|Whh1]
  u16* xcat  = (u16*)alloc((size_t)B_ * XW * 2);          // [pred|h0_a|h0_b]
  u16* EMB   = (u16*)alloc((size_t)S_ * B_ * E_ * 2);     // pre-gathered embeddings
  u16* x1cat = (u16*)alloc((size_t)B_ * X1W * 2);         // [x1_a|x1_b|h1_a|h1_b]
  float* c0   = (float*)alloc((size_t)B_ * H_ * 4);
  float* c1   = (float*)alloc((size_t)B_ * H_ * 4);
  float* bs0  = (float*)alloc((size_t)S_ * G4H * 4);
  float* bs1  = (float*)alloc((size_t)S_ * G4H * 4);

  // -------- phase A: weight conversion + state init ---------------------------
  pack_gw4<K0_, 1024, 1536, D0_, H_><<<2912, 256, 0, stream>>>(Wih0, Whh0, WC0);
  pack_gw4<KX1,  512, 1024, H_,  H_><<<1792, 256, 0, stream>>>(Wih1, Whh1, WC1);
  pack_hw4<K0_, false><<<728, 256, 0, stream>>>(hwW0,  WHLw, 0);
  pack_hw4<D0_, true ><<<728, 256, 0, stream>>>(linW0, WHLw, 16);
  pack_predz4<<<1024, 256, 0, stream>>>(pred, xcat);
  xgather<<<B_, E_, 0, stream>>>(emb, labels, EMB);
  bias_sum<<<56, 256, 0, stream>>>(bih0, bhh0, bs0, S_ * G4H);
  bias_sum<<<56, 256, 0, stream>>>(bih1, bhh1, bs1, S_ * G4H);
  zero_f<<<256, 256, 0, stream>>>(c0, B_ * H_);
  zero_f<<<256, 256, 0, stream>>>(c1, B_ * H_);
  zero_u16k<<<512, 256, 0, stream>>>(x1cat, B_ * X1W);

  // -------- role builders -----------------------------------------------------
  auto mkA = [&](int s) {              // G0_s: [pred|h0_{s-1}|emb_s] @ WC0_s^T
    GemmP P;
    P.r0 = xcat;                                 P.ld0 = XW;  P.t1 = 16;
    P.r1 = xcat + 1024 + ((s + 1) & 1) * 512;    P.ld1 = XW;  P.t2 = 24;
    P.r2 = EMB + (size_t)s * B_ * E_;            P.ld2 = E_;
    P.W = WC0 + (size_t)s * G4H * K0_;           P.ldw = K0_; P.nt = 26;
    P.ntn = 16; P.cpx = 64;
    P.bsum = bs0 + (size_t)s * G4H; P.cbuf = c0;
    P.hdst = xcat; P.hld = XW; P.hoff = 1024 + (s & 1) * 512;
    P.hf32 = nullptr; P.h0src = xcat; P.h0ld = 0; P.mode = 0;
    return P;
  };
  auto mkB = [&](int s) {              // WHL_s: [pred|h0_s|emb_s] @ WHL_s^T
    GemmP P;
    P.r0 = xcat;                                 P.ld0 = XW;  P.t1 = 16;
    P.r1 = xcat + 1024 + (s & 1) * 512;          P.ld1 = XW;  P.t2 = 24;
    P.r2 = EMB + (size_t)s * B_ * E_;            P.ld2 = E_;
    P.W = WHLw + (size_t)s * 1024 * K0_;         P.ldw = K0_; P.nt = 26;
    P.ntn = 8; P.cpx = 32;
    P.bsum = hwb0 + (size_t)s * H_; P.cbuf = nullptr;
    P.hdst = x1cat; P.hld = X1W; P.hoff = (s & 1) * 512;
    P.hf32 = nullptr;
    P.h0src = xcat + 1024 + (s & 1) * 512; P.h0ld = XW; P.mode = 1;
    return P;
  };
  auto mkC = [&](int s) {              // G1_s: [x1_s|h1_{s-1}] @ WC1_s^T
    GemmP P;
    P.r0 = x1cat + (s & 1) * 512;                P.ld0 = X1W; P.t1 = 8;
    P.r1 = x1cat + 1024 + ((s + 1) & 1) * 512;   P.ld1 = X1W; P.t2 = 16;
    P.r2 = P.r0;                                 P.ld2 = X1W;
    P.W = WC1 + (size_t)s * G4H * KX1;           P.ldw = KX1; P.nt = 16;
    P.ntn = 16; P.cpx = 64;
    P.bsum = bs1 + (size_t)s * G4H; P.cbuf = c1;
    P.hdst = x1cat; P.hld = X1W; P.hoff = 1024 + (s & 1) * 512;
    P.hf32 = (s == 6) ? out : nullptr; P.h0src = x1cat; P.h0ld = 0; P.mode = 0;
    return P;
  };

  // -------- pipelined slot loop: L_k = { G0_k , WHL_{k-1} , G1_{k-2} } --------
  for (int k = 0; k <= 8; ++k) {
    const int nA = (k <= 6) ? 512 : 0;
    const int nB = (k >= 1 && k <= 7) ? 256 : 0;
    const int nC = (k >= 2) ? 512 : 0;
    GemmP pa, pb, pc;
    if (nA) pa = mkA(k);
    if (nB) pb = mkB(k - 1);
    if (nC) pc = mkC(k - 2);
    GemmP any = nA ? pa : (nB ? pb : pc);
    if (!nA) pa = any;
    if (!nB) pb = any;
    if (!nC) pc = any;
    gemm_multi<<<nA + nB + nC, 256, 0, stream>>>(pa, pb, pc, nA, nA + nB);
  }
}

// Round 9
// 657.170 us; speedup vs baseline: 1.8532x; 1.0044x over previous
//
#include <hip/hip_runtime.h>
#include <stdint.h>

typedef unsigned short u16;

#define S_   7
#define B_   4096
#define D_   1024
#define E_   128
#define H_   512
#define V_   200
#define D0_  1152   // D+E
#define K0_  1664   // layer-0 GEMM K: pred 1024 + h0 512 + emb 128
#define KX1  1024   // layer-1 GEMM K: x1 512 + h1 512
#define G4H  2048   // 4H
#define XW   2048   // xcat width: [pred(1024) | h0_a(512) | h0_b(512)]
#define X1W  2048   // x1cat width: [x1_a | x1_b | h1_a | h1_b]

typedef __bf16 bf16x8 __attribute__((ext_vector_type(8)));
typedef float  f32x4  __attribute__((ext_vector_type(4)));
typedef u16    u16x8  __attribute__((ext_vector_type(8)));

__device__ __forceinline__ u16 f2bf(float f) {
  union { float f; uint32_t u; } v; v.f = f;
  uint32_t r = v.u + 0x7fffu + ((v.u >> 16) & 1u);   // RNE
  return (u16)(r >> 16);
}
__device__ __forceinline__ float bf2f(u16 b) {
  union { uint32_t u; float f; } v; v.u = ((uint32_t)b) << 16;
  return v.f;
}
__device__ __forceinline__ float sigmoidf_(float x) { return 1.0f / (1.0f + __expf(-x)); }
__device__ __forceinline__ float tanhf_(float x) {
  float t = __expf(-2.f * fabsf(x));
  return copysignf((1.f - t) / (1.f + t), x);
}

__device__ __forceinline__ void glds16(const u16* g, u16* l) {
  __builtin_amdgcn_global_load_lds(
      (const __attribute__((address_space(1))) uint32_t*)g,
      (__attribute__((address_space(3))) uint32_t*)l, 16, 0, 0);
}

__device__ __forceinline__ void cvt8s(const float* src, u16* dst) {
  const float4* p = (const float4*)src;
  float4 x = p[0], y = p[1];
  u16x8 o;
  o[0]=f2bf(x.x); o[1]=f2bf(x.y); o[2]=f2bf(x.z); o[3]=f2bf(x.w);
  o[4]=f2bf(y.x); o[5]=f2bf(y.y); o[6]=f2bf(y.z); o[7]=f2bf(y.w);
  *(u16x8*)dst = o;
}

// ---------- pack device fns (slot-based pointers passed in) ------------------
// gates: src row r = g*512+j -> dst row (j>>4)*64 + g*16 + (j&15); K-order
// [Wih 0..P1 | Whh 0..P2-P1 | Wih P1..]
__device__ __forceinline__ void pk_gates(const float* __restrict__ Wih,
                                         const float* __restrict__ Whh,
                                         u16* __restrict__ dst,
                                         int idx, int stride, int NG, int KK,
                                         int P1, int P2, int KA, int KB) {
  #pragma unroll
  for (int u = 0; u < 4; ++u) {
    int i = idx + u * stride;
    int r = i / NG, kg = i - r * NG;
    int k8 = kg * 8;
    int g = r >> 9, j = r & 511;
    long drow = (j >> 4) * 64 + g * 16 + (j & 15);
    const float* sp = (k8 < P1) ? Wih + (long)r * KA + k8
                    : (k8 < P2) ? Whh + (long)r * KB + (k8 - P1)
                                : Wih + (long)r * KA + P1 + (k8 - P2);
    cvt8s(sp, &dst[drow * KK + k8]);
  }
}
// hw/lin: dst row (j>>4)*32 + off16 + (j&15); K-order [x-pred | h(or zero) | x-emb]
__device__ __forceinline__ void pk_hw(const float* __restrict__ src,
                                      u16* __restrict__ dst,
                                      int idx, int stride, int off16, int KS, bool Z2) {
  #pragma unroll
  for (int u = 0; u < 4; ++u) {
    int i = idx + u * stride;
    int r = i / 208, kg = i - r * 208;
    int k8 = kg * 8;
    long drow = ((r & 511) >> 4) * 32 + off16 + (r & 15);
    u16* d = &dst[drow * K0_ + k8];
    if (Z2 && k8 >= 1024 && k8 < 1536) {
      u16x8 z = {};
      *(u16x8*)d = z;
    } else {
      const float* sp = (k8 < 1024) ? src + (long)r * KS + k8
                      : (k8 < 1536) ? src + (long)r * KS + 1152 + (k8 - 1024)
                                    : src + (long)r * KS + 1024 + (k8 - 1536);
      cvt8s(sp, d);
    }
  }
}

// ---------- pred pack into xcat[:,0..1024), zeros in both h0 slots -----------
__global__ void pack_predz4(const float* __restrict__ pred, u16* __restrict__ dst) {
  const int NG = XW / 8;   // 256
  const int stride = gridDim.x * 256;
  int idx = blockIdx.x * 256 + threadIdx.x;
  #pragma unroll
  for (int u = 0; u < 4; ++u) {
    int i = idx + u * stride;
    int row = i / NG, kg = i - row * NG;
    int k8 = kg * 8;
    u16* d = &dst[(long)row * XW + k8];
    if (k8 < 1024) {
      cvt8s(pred + (long)row * D_ + k8, d);
    } else {
      u16x8 z = {};
      *(u16x8*)d = z;
    }
  }
}

// ---------- pre-gather ALL slots' embeddings: EMB[s][b][e] bf16 --------------
__global__ void xgather(const float* __restrict__ emb, const int* __restrict__ labels,
                        u16* __restrict__ EMB) {
  int b = blockIdx.x;
  int e = threadIdx.x;
  #pragma unroll
  for (int s = 0; s < S_; ++s) {
    int ix = labels[s * B_ + b];
    EMB[((long)(s * B_ + b)) * E_ + e] = f2bf(emb[((long)(s * V_ + ix)) * E_ + e]);
  }
}

__global__ void bias_sum(const float* __restrict__ a, const float* __restrict__ b,
                         float* __restrict__ o, int n) {
  int i = blockIdx.x * 256 + threadIdx.x;
  if (i < n) o[i] = a[i] + b[i];
}
__global__ void zero_f(float* __restrict__ p, int n) {
  for (int i = blockIdx.x * 256 + threadIdx.x; i < n; i += gridDim.x * 256) p[i] = 0.f;
}
__global__ void zero_u16k(u16* __restrict__ p, int n) {
  for (int i = blockIdx.x * 256 + threadIdx.x; i < n; i += gridDim.x * 256) p[i] = 0;
}

// ---------------- multi-role fused GEMM + pack riders ------------------------
// GEMM engine: 128x128 tile, BK=32, A+W via global_load_lds into double-buffered
// LDS (32 KiB total -> 4 blocks/CU with launch_bounds(256,4)), prefetch-(t+1)-
// then-compute-t, single syncthreads per step, XOR swizzle seg^=(row>>1)&3
// (conflict-free for 64B rows), 2D-chunked XCD remap. 4 waves (2x2 of 64x64).
// mode 0: LSTM cell epilogue (gate-interleaved W; acc[m][0..3] = i,f,g,o).
// mode 1: highway epilogue ([hw16|lin16] W; h0 read from h0src).
// Rider blocks (b >= nABC) pack slot-(k+1) weights in the launch's drain tail.
struct GemmP {
  const u16 *r0, *r1, *r2, *W;
  const float *bsum;
  float *cbuf;
  u16 *hdst;
  float *hf32;
  const u16 *h0src;
  int ld0, ld1, ld2, t1, t2, ldw, nt, ntn, tnw_sh, ncc_sh, tmw, hld, hoff, h0ld, mode;
};
struct PackP {
  const float *wih0, *whh0, *wih1, *whh1, *hww, *linw;
  u16 *wc0, *wc1, *whl;
};

__global__ __launch_bounds__(256, 4)
void gemm_multi(GemmP pa, GemmP pb, GemmP pc, PackP pk, int nA, int nAB, int nABC) {
  const int b   = blockIdx.x;
  const int tid = threadIdx.x;

  if (b >= nABC) {   // ---- pack rider ----
    int rb = b - nABC;
    if (rb < 416) {
      pk_gates(pk.wih0, pk.whh0, pk.wc0, rb * 256 + tid, 416 * 256,
               208, K0_, 1024, 1536, D0_, H_);
    } else if (rb < 672) {
      pk_gates(pk.wih1, pk.whh1, pk.wc1, (rb - 416) * 256 + tid, 256 * 256,
               128, KX1, 512, 1024, H_, H_);
    } else {
      int sb = rb - 672;
      if (sb < 104) pk_hw(pk.hww,  pk.whl, sb * 256 + tid,        104 * 256, 0,  K0_, false);
      else          pk_hw(pk.linw, pk.whl, (sb - 104) * 256 + tid, 104 * 256, 16, D0_, true);
    }
    return;
  }

  __shared__ __align__(16) u16 lds[4 * 4096];   // A dbuf 16KB + W dbuf 16KB
  GemmP P = pc; int base = nAB;
  if (b < nAB) { P = pb; base = nA; }
  if (b < nA)  { P = pa; base = 0; }
  const int bidx = b - base;

  u16* lA = lds;
  u16* lW = lds + 2 * 4096;
  const int lane = tid & 63;
  const int wave = tid >> 6;
  // 2D-chunked XCD remap: xcd gets a tmw x tnw tile chunk (bijective)
  const int xcd = bidx & 7, ci = bidx >> 3;
  const int tn = ((xcd & ((1 << P.ncc_sh) - 1)) << P.tnw_sh) | (ci & ((1 << P.tnw_sh) - 1));
  const int tm = (xcd >> P.ncc_sh) * P.tmw + (ci >> P.tnw_sh);
  const long row0 = (long)tm * 128;
  const long col0 = (long)tn * 128;
  const int wm = (wave >> 1) * 64;
  const int wn = (wave & 1) * 64;
  const int fr = lane & 15;
  const int hi = lane >> 4;

  // staging: per round q (2 rounds) wave covers rows q*64 + wave*16 + (lane>>2);
  // source col pre-swizzled (seg ^ (row>>1)&3) so linear DMA dest + swizzled
  // ds_read return the right element.
  const int s_row = wave * 16 + (lane >> 2);
  const int scol = ((lane & 3) ^ ((lane >> 3) & 3)) * 8;
  const u16* gr0 = P.r0 + (row0 + s_row) * (long)P.ld0 + scol;
  const u16* gr1 = P.r1 + (row0 + s_row) * (long)P.ld1 + scol;
  const u16* gr2 = P.r2 + (row0 + s_row) * (long)P.ld2 + scol;
  const u16* gw  = P.W  + (col0 + s_row) * (long)P.ldw + scol;
  const int dst0 = wave * 512 + lane * 8;

  auto stage = [&](int t, int buf) {
    const u16* g; long ld;
    if (t < P.t1)      { g = gr0 + (long)t * 32;          ld = P.ld0; }
    else if (t < P.t2) { g = gr1 + (long)(t - P.t1) * 32; ld = P.ld1; }
    else               { g = gr2 + (long)(t - P.t2) * 32; ld = P.ld2; }
    const u16* gww = gw + (long)t * 32;
    u16* dA = lA + buf * 4096 + dst0;
    u16* dW = lW + buf * 4096 + dst0;
    glds16(g,           dA);
    glds16(g + 64 * ld, dA + 2048);
    glds16(gww,                      dW);
    glds16(gww + 64 * (long)P.ldw,   dW + 2048);
  };

  const int koff = (hi ^ ((fr >> 1) & 3)) * 8;
  int aoff[4], woff[4];
  #pragma unroll
  for (int m = 0; m < 4; ++m) aoff[m] = (wm + m * 16 + fr) * 32 + koff;
  #pragma unroll
  for (int n = 0; n < 4; ++n) woff[n] = (wn + n * 16 + fr) * 32 + koff;

  f32x4 acc[4][4] = {};
  const int nt = P.nt;

  stage(0, 0);

  for (int t = 0; t < nt; ++t) {
    __syncthreads();                  // tile t DMA complete in buf (t&1)
    if (t + 1 < nt) stage(t + 1, (t + 1) & 1);
    const u16* Ab = lA + (t & 1) * 4096;
    const u16* Wb = lW + (t & 1) * 4096;
    bf16x8 af[4], wf[4];
    #pragma unroll
    for (int m = 0; m < 4; ++m) af[m] = *(const bf16x8*)&Ab[aoff[m]];
    #pragma unroll
    for (int n = 0; n < 4; ++n) wf[n] = *(const bf16x8*)&Wb[woff[n]];
    #pragma unroll
    for (int m = 0; m < 4; ++m)
      #pragma unroll
      for (int n = 0; n < 4; ++n)
        acc[m][n] = __builtin_amdgcn_mfma_f32_16x16x32_bf16(af[m], wf[n], acc[m][n], 0, 0, 0);
  }

  const int cr = (lane >> 4) * 4;
  const int jg = wn >> 6;   // 0 or 1

  if (P.mode == 0) {
    const int j = tn * 32 + jg * 16 + fr;
    const float bi = P.bsum[j], bf = P.bsum[512 + j];
    const float bg = P.bsum[1024 + j], bo = P.bsum[1536 + j];
    #pragma unroll
    for (int m = 0; m < 4; ++m) {
      const long rbase = row0 + wm + m * 16 + cr;
      #pragma unroll
      for (int r = 0; r < 4; ++r) {
        const long ri = rbase + r;
        float gi = acc[m][0][r] + bi;
        float gf = acc[m][1][r] + bf;
        float gg = acc[m][2][r] + bg;
        float go = acc[m][3][r] + bo;
        float cv = P.cbuf[ri * H_ + j];
        float cn = sigmoidf_(gf) * cv + sigmoidf_(gi) * tanhf_(gg);
        float hn = sigmoidf_(go) * tanhf_(cn);
        P.cbuf[ri * H_ + j] = cn;
        P.hdst[ri * P.hld + P.hoff + j] = f2bf(hn);
        if (P.hf32) P.hf32[ri * H_ + j] = hn;
      }
    }
  } else {
    #pragma unroll
    for (int pp = 0; pp < 2; ++pp) {
      const int j = tn * 64 + jg * 32 + pp * 16 + fr;
      const float bj = P.bsum[j];
      #pragma unroll
      for (int m = 0; m < 4; ++m) {
        const long rbase = row0 + wm + m * 16 + cr;
        #pragma unroll
        for (int r = 0; r < 4; ++r) {
          const long ri = rbase + r;
          float gv = sigmoidf_(acc[m][2 * pp][r] + bj);
          float h0 = bf2f(P.h0src[ri * (long)P.h0ld + j]);
          float x1 = gv * h0 + (1.f - gv) * acc[m][2 * pp + 1][r];
          P.hdst[ri * P.hld + P.hoff + j] = f2bf(x1);
        }
      }
    }
  }
}

extern "C" void kernel_launch(void* const* d_in, const int* in_sizes, int n_in,
                              void* d_out, int out_size, void* d_ws, size_t ws_size,
                              hipStream_t stream) {
  const float* pred   = (const float*)d_in[0];
  const int*   labels = (const int*)d_in[1];
  const float* emb    = (const float*)d_in[2];
  const float* Wih0   = (const float*)d_in[3];
  const float* Whh0   = (const float*)d_in[4];
  const float* bih0   = (const float*)d_in[5];
  const float* bhh0   = (const float*)d_in[6];
  const float* hwW0   = (const float*)d_in[7];
  const float* hwb0   = (const float*)d_in[8];
  const float* linW0  = (const float*)d_in[9];
  const float* Wih1   = (const float*)d_in[10];
  const float* Whh1   = (const float*)d_in[11];
  const float* bih1   = (const float*)d_in[12];
  const float* bhh1   = (const float*)d_in[13];
  float* out = (float*)d_out;

  char* ws = (char*)d_ws;
  size_t off = 0;
  auto alloc = [&](size_t bytes) {
    char* p = ws + off;
    off = (off + bytes + 255) & ~(size_t)255;
    return p;
  };
  u16* WC0   = (u16*)alloc((size_t)S_ * G4H * K0_ * 2);   // gate-ilv [Wp|Wh|We]
  u16* WHLw  = (u16*)alloc((size_t)S_ * 1024 * K0_ * 2);  // [hw16|lin16]
  u16* WC1   = (u16*)alloc((size_t)S_ * G4H * KX1 * 2);   // gate-ilv [Wih1|Whh1]
  u16* xcat  = (u16*)alloc((size_t)B_ * XW * 2);          // [pred|h0_a|h0_b]
  u16* EMB   = (u16*)alloc((size_t)S_ * B_ * E_ * 2);     // pre-gathered embeddings
  u16* x1cat = (u16*)alloc((size_t)B_ * X1W * 2);         // [x1_a|x1_b|h1_a|h1_b]
  float* c0   = (float*)alloc((size_t)B_ * H_ * 4);
  float* c1   = (float*)alloc((size_t)B_ * H_ * 4);
  float* bs0  = (float*)alloc((size_t)S_ * G4H * 4);
  float* bs1  = (float*)alloc((size_t)S_ * G4H * 4);

  auto mkPk = [&](int s) {
    PackP K;
    K.wih0 = Wih0 + (size_t)s * G4H * D0_;
    K.whh0 = Whh0 + (size_t)s * G4H * H_;
    K.wih1 = Wih1 + (size_t)s * G4H * H_;
    K.whh1 = Whh1 + (size_t)s * G4H * H_;
    K.hww  = hwW0 + (size_t)s * H_ * K0_;
    K.linw = linW0 + (size_t)s * H_ * D0_;
    K.wc0  = WC0  + (size_t)s * G4H * K0_;
    K.wc1  = WC1  + (size_t)s * G4H * KX1;
    K.whl  = WHLw + (size_t)s * 1024 * K0_;
    return K;
  };

  // -------- phase A: slot-0 pack (rider-only launch) + state init -------------
  GemmP z = {};
  gemm_multi<<<880, 256, 0, stream>>>(z, z, z, mkPk(0), 0, 0, 0);
  pack_predz4<<<1024, 256, 0, stream>>>(pred, xcat);
  xgather<<<B_, E_, 0, stream>>>(emb, labels, EMB);
  bias_sum<<<56, 256, 0, stream>>>(bih0, bhh0, bs0, S_ * G4H);
  bias_sum<<<56, 256, 0, stream>>>(bih1, bhh1, bs1, S_ * G4H);
  zero_f<<<256, 256, 0, stream>>>(c0, B_ * H_);
  zero_f<<<256, 256, 0, stream>>>(c1, B_ * H_);
  zero_u16k<<<2048, 256, 0, stream>>>(x1cat, B_ * X1W);

  // -------- role builders -----------------------------------------------------
  auto mkA = [&](int s) {              // G0_s: [pred|h0_{s-1}|emb_s] @ WC0_s^T
    GemmP P;
    P.r0 = xcat;                               P.ld0 = XW;  P.t1 = 32;
    P.r1 = xcat + 1024 + ((s + 1) & 1) * 512;  P.ld1 = XW;  P.t2 = 48;
    P.r2 = EMB + (size_t)s * B_ * E_;          P.ld2 = E_;
    P.W = WC0 + (size_t)s * G4H * K0_;         P.ldw = K0_; P.nt = 52;
    P.ntn = 16; P.tnw_sh = 3; P.ncc_sh = 1; P.tmw = 8;
    P.bsum = bs0 + (size_t)s * G4H; P.cbuf = c0;
    P.hdst = xcat; P.hld = XW; P.hoff = 1024 + (s & 1) * 512;
    P.hf32 = nullptr; P.h0src = xcat; P.h0ld = 0; P.mode = 0;
    return P;
  };
  auto mkB = [&](int s) {              // WHL_s: [pred|h0_s|emb_s] @ WHL_s^T
    GemmP P;
    P.r0 = xcat;                               P.ld0 = XW;  P.t1 = 32;
    P.r1 = xcat + 1024 + (s & 1) * 512;        P.ld1 = XW;  P.t2 = 48;
    P.r2 = EMB + (size_t)s * B_ * E_;          P.ld2 = E_;
    P.W = WHLw + (size_t)s * 1024 * K0_;       P.ldw = K0_; P.nt = 52;
    P.ntn = 8; P.tnw_sh = 2; P.ncc_sh = 1; P.tmw = 8;
    P.bsum = hwb0 + (size_t)s * H_; P.cbuf = nullptr;
    P.hdst = x1cat; P.hld = X1W; P.hoff = (s & 1) * 512;
    P.hf32 = nullptr;
    P.h0src = xcat + 1024 + (s & 1) * 512; P.h0ld = XW; P.mode = 1;
    return P;
  };
  auto mkC = [&](int s) {              // G1_s: [x1_s|h1_{s-1}] @ WC1_s^T
    GemmP P;
    P.r0 = x1cat + (s & 1) * 512;              P.ld0 = X1W; P.t1 = 16;
    P.r1 = x1cat + 1024 + ((s + 1) & 1) * 512; P.ld1 = X1W; P.t2 = 32;
    P.r2 = P.r0;                               P.ld2 = X1W;
    P.W = WC1 + (size_t)s * G4H * KX1;         P.ldw = KX1; P.nt = 32;
    P.ntn = 16; P.tnw_sh = 3; P.ncc_sh = 1; P.tmw = 8;
    P.bsum = bs1 + (size_t)s * G4H; P.cbuf = c1;
    P.hdst = x1cat; P.hld = X1W; P.hoff = 1024 + (s & 1) * 512;
    P.hf32 = (s == 6) ? out : nullptr; P.h0src = x1cat; P.h0ld = 0; P.mode = 0;
    return P;
  };

  // -------- pipelined slot loop: L_k = { G0_k, WHL_{k-1}, G1_{k-2}, pack_{k+1} }
  for (int k = 0; k <= 8; ++k) {
    const int nA = (k <= 6) ? 512 : 0;
    const int nB = (k >= 1 && k <= 7) ? 256 : 0;
    const int nC = (k >= 2) ? 512 : 0;
    const int nD = (k <= 5) ? 880 : 0;
    GemmP pa, pb, pc;
    if (nA) pa = mkA(k);
    if (nB) pb = mkB(k - 1);
    if (nC) pc = mkC(k - 2);
    GemmP any = nA ? pa : (nB ? pb : pc);
    if (!nA) pa = any;
    if (!nB) pb = any;
    if (!nC) pc = any;
    PackP pk = mkPk(nD ? (k + 1) : 0);
    gemm_multi<<<nA + nB + nC + nD, 256, 0, stream>>>(pa, pb, pc, pk,
                                                      nA, nA + nB, nA + nB + nC);
  }
}

// Round 10
// 626.553 us; speedup vs baseline: 1.9438x; 1.0489x over previous
//
#include <hip/hip_runtime.h>
#include <stdint.h>

typedef unsigned short u16;

#define S_   7
#define B_   4096
#define D_   1024
#define E_   128
#define H_   512
#define V_   200
#define D0_  1152   // D+E
#define K0_  1664   // layer-0 GEMM K: pred 1024 + h0 512 + emb 128
#define KX1  1024   // layer-1 GEMM K: x1 512 + h1 512
#define G4H  2048   // 4H
#define XW   2048   // xcat width: [pred(1024) | h0_a(512) | h0_b(512)]
#define X1W  2048   // x1cat width: [x1_a | x1_b | h1_a | h1_b]

typedef __bf16 bf16x8 __attribute__((ext_vector_type(8)));
typedef float  f32x4  __attribute__((ext_vector_type(4)));
typedef u16    u16x8  __attribute__((ext_vector_type(8)));

__device__ __forceinline__ u16 f2bf(float f) {
  union { float f; uint32_t u; } v; v.f = f;
  uint32_t r = v.u + 0x7fffu + ((v.u >> 16) & 1u);   // RNE
  return (u16)(r >> 16);
}
__device__ __forceinline__ float bf2f(u16 b) {
  union { uint32_t u; float f; } v; v.u = ((uint32_t)b) << 16;
  return v.f;
}
__device__ __forceinline__ float sigmoidf_(float x) { return 1.0f / (1.0f + __expf(-x)); }
__device__ __forceinline__ float tanhf_(float x) {
  float t = __expf(-2.f * fabsf(x));
  return copysignf((1.f - t) / (1.f + t), x);
}

__device__ __forceinline__ void glds16(const u16* g, u16* l) {
  __builtin_amdgcn_global_load_lds(
      (const __attribute__((address_space(1))) uint32_t*)g,
      (__attribute__((address_space(3))) uint32_t*)l, 16, 0, 0);
}

__device__ __forceinline__ void cvt8s(const float* src, u16* dst) {
  const float4* p = (const float4*)src;
  float4 x = p[0], y = p[1];
  u16x8 o;
  o[0]=f2bf(x.x); o[1]=f2bf(x.y); o[2]=f2bf(x.z); o[3]=f2bf(x.w);
  o[4]=f2bf(y.x); o[5]=f2bf(y.y); o[6]=f2bf(y.z); o[7]=f2bf(y.w);
  *(u16x8*)dst = o;
}

// ---------- pack device fns (per-slot pointers passed in) --------------------
// gates: src row r = g*512+j -> dst row (j>>4)*64 + g*16 + (j&15); K-order
// [Wih 0..P1 | Whh 0..P2-P1 | Wih P1..]
__device__ __forceinline__ void pk_gates(const float* __restrict__ Wih,
                                         const float* __restrict__ Whh,
                                         u16* __restrict__ dst,
                                         int idx, int stride, int NG, int KK,
                                         int P1, int P2, int KA, int KB) {
  #pragma unroll
  for (int u = 0; u < 4; ++u) {
    int i = idx + u * stride;
    int r = i / NG, kg = i - r * NG;
    int k8 = kg * 8;
    int g = r >> 9, j = r & 511;
    long drow = (j >> 4) * 64 + g * 16 + (j & 15);
    const float* sp = (k8 < P1) ? Wih + (long)r * KA + k8
                    : (k8 < P2) ? Whh + (long)r * KB + (k8 - P1)
                                : Wih + (long)r * KA + P1 + (k8 - P2);
    cvt8s(sp, &dst[drow * KK + k8]);
  }
}
// hw/lin: dst row (j>>4)*32 + off16 + (j&15); K-order [x-pred | h(or zero) | x-emb]
__device__ __forceinline__ void pk_hw(const float* __restrict__ src,
                                      u16* __restrict__ dst,
                                      int idx, int stride, int off16, int KS, bool Z2) {
  #pragma unroll
  for (int u = 0; u < 4; ++u) {
    int i = idx + u * stride;
    int r = i / 208, kg = i - r * 208;
    int k8 = kg * 8;
    long drow = ((r & 511) >> 4) * 32 + off16 + (r & 15);
    u16* d = &dst[drow * K0_ + k8];
    if (Z2 && k8 >= 1024 && k8 < 1536) {
      u16x8 z = {};
      *(u16x8*)d = z;
    } else {
      const float* sp = (k8 < 1024) ? src + (long)r * KS + k8
                      : (k8 < 1536) ? src + (long)r * KS + 1152 + (k8 - 1024)
                                    : src + (long)r * KS + 1024 + (k8 - 1536);
      cvt8s(sp, d);
    }
  }
}

// ---------- pred pack into xcat[:,0..1024), zeros in both h0 slots -----------
__global__ void pack_predz4(const float* __restrict__ pred, u16* __restrict__ dst) {
  const int NG = XW / 8;   // 256
  const int stride = gridDim.x * 256;
  int idx = blockIdx.x * 256 + threadIdx.x;
  #pragma unroll
  for (int u = 0; u < 4; ++u) {
    int i = idx + u * stride;
    int row = i / NG, kg = i - row * NG;
    int k8 = kg * 8;
    u16* d = &dst[(long)row * XW + k8];
    if (k8 < 1024) {
      cvt8s(pred + (long)row * D_ + k8, d);
    } else {
      u16x8 z = {};
      *(u16x8*)d = z;
    }
  }
}

// ---------- pre-gather ALL slots' embeddings: EMB[s][b][e] bf16 --------------
__global__ void xgather(const float* __restrict__ emb, const int* __restrict__ labels,
                        u16* __restrict__ EMB) {
  int b = blockIdx.x;
  int e = threadIdx.x;
  #pragma unroll
  for (int s = 0; s < S_; ++s) {
    int ix = labels[s * B_ + b];
    EMB[((long)(s * B_ + b)) * E_ + e] = f2bf(emb[((long)(s * V_ + ix)) * E_ + e]);
  }
}

__global__ void bias_sum(const float* __restrict__ a, const float* __restrict__ b,
                         float* __restrict__ o, int n) {
  int i = blockIdx.x * 256 + threadIdx.x;
  if (i < n) o[i] = a[i] + b[i];
}
__global__ void zero_f(float* __restrict__ p, int n) {
  for (int i = blockIdx.x * 256 + threadIdx.x; i < n; i += gridDim.x * 256) p[i] = 0.f;
}
__global__ void zero_u16k(u16* __restrict__ p, int n) {
  for (int i = blockIdx.x * 256 + threadIdx.x; i < n; i += gridDim.x * 256) p[i] = 0;
}

// ---------------- multi-role deep-pipelined GEMM + pack riders ---------------
// Engine: 256x128 tile, BK=64, 512 threads = 8 waves (4M x 2N of 64x64 each),
// 16x16x32 MFMA. 3-deep LDS ring (144 KB), depth-2 prefetch, counted
// "s_waitcnt vmcnt(6); s_barrier" per K-tile (in-flight loads survive the
// barrier -- never drained to 0 mid-loop), s_setprio(1) around the MFMA
// cluster. Staging + XOR swizzle + fragment math identical to prior rounds.
// WAR safety: each wave's tile-(t-1) ds_reads are lgkm-drained before its
// iter-t barrier (compiler drains before last MFMA use), so stage(t+2)
// issued after the barrier cannot overwrite data still being read.
// mode 0: LSTM cell epilogue (gate-interleaved W; acc[m][0..3] = i,f,g,o).
// mode 1: highway epilogue ([hw16|lin16] W; h0 read from h0src).
// Rider blocks (b >= nABC) pack slot-(k+1) weights in the launch's drain tail.
struct GemmP {
  const u16 *r0, *r1, *r2, *W;
  const float *bsum;
  float *cbuf;
  u16 *hdst;
  float *hf32;
  const u16 *h0src;
  int ld0, ld1, ld2, t1, t2, ldw, nt, ntn, tnw_sh, ncc_sh, tmw, hld, hoff, h0ld, mode;
};
struct PackP {
  const float *wih0, *whh0, *wih1, *whh1, *hww, *linw;
  u16 *wc0, *wc1, *whl;
};

__global__ __launch_bounds__(512, 2)
void gemm_multi(GemmP pa, GemmP pb, GemmP pc, PackP pk, int nA, int nAB, int nABC) {
  const int b   = blockIdx.x;
  const int tid = threadIdx.x;

  if (b >= nABC) {   // ---- pack rider (512 threads, ILP 4) ----
    int rb = b - nABC;
    if (rb < 208) {
      pk_gates(pk.wih0, pk.whh0, pk.wc0, rb * 512 + tid, 208 * 512,
               208, K0_, 1024, 1536, D0_, H_);
    } else if (rb < 336) {
      pk_gates(pk.wih1, pk.whh1, pk.wc1, (rb - 208) * 512 + tid, 128 * 512,
               128, KX1, 512, 1024, H_, H_);
    } else if (rb < 388) {
      pk_hw(pk.hww,  pk.whl, (rb - 336) * 512 + tid, 52 * 512, 0,  K0_, false);
    } else {
      pk_hw(pk.linw, pk.whl, (rb - 388) * 512 + tid, 52 * 512, 16, D0_, true);
    }
    return;
  }

  // LDS ring: A 3 x 16384 u16 (256x64), W 3 x 8192 u16 (128x64) = 144 KiB
  __shared__ __align__(16) u16 lds[3 * 16384 + 3 * 8192];
  u16* lA = lds;
  u16* lW = lds + 3 * 16384;

  GemmP P = pc; int base = nAB;
  if (b < nAB) { P = pb; base = nA; }
  if (b < nA)  { P = pa; base = 0; }
  const int bidx = b - base;

  const int lane = tid & 63;
  const int wave = tid >> 6;          // 0..7
  // 2D-chunked XCD remap (bijective for our grid sizes)
  const int xcd = bidx & 7, ci = bidx >> 3;
  const int tn = ((xcd & ((1 << P.ncc_sh) - 1)) << P.tnw_sh) | (ci & ((1 << P.tnw_sh) - 1));
  const int tm = (xcd >> P.ncc_sh) * P.tmw + (ci >> P.tnw_sh);
  const long row0 = (long)tm * 256;
  const long col0 = (long)tn * 128;
  const int wm = (wave >> 1) * 64;    // 0,64,128,192
  const int wn = (wave & 1) * 64;     // 0,64
  const int fr = lane & 15;
  const int fk = (lane >> 4) * 8;

  // staging: wave covers rows [i*64 + wave*8, +8) per issue; source col
  // pre-swizzled (seg ^ row&7) so linear DMA dest + swizzled ds_read match.
  const int srow = wave * 8 + (lane >> 3);
  const int scol = ((lane & 7) ^ ((lane >> 3) & 7)) * 8;
  const u16* gr0 = P.r0 + (row0 + srow) * (long)P.ld0 + scol;
  const u16* gr1 = P.r1 + (row0 + srow) * (long)P.ld1 + scol;
  const u16* gr2 = P.r2 + (row0 + srow) * (long)P.ld2 + scol;
  const u16* gw  = P.W  + (col0 + srow) * (long)P.ldw + scol;
  const int dst0 = wave * 512 + lane * 8;

  auto stage = [&](int t, int buf) {   // 6 glds16 per thread (4 A + 2 W)
    const u16* g; long ld;
    if (t < P.t1)      { g = gr0 + (long)t * 64;          ld = P.ld0; }
    else if (t < P.t2) { g = gr1 + (long)(t - P.t1) * 64; ld = P.ld1; }
    else               { g = gr2 + (long)(t - P.t2) * 64; ld = P.ld2; }
    const u16* gww = gw + (long)t * 64;
    u16* dA = lA + buf * 16384 + dst0;
    u16* dW = lW + buf * 8192 + dst0;
    #pragma unroll
    for (int i = 0; i < 4; ++i) glds16(g + (long)(i * 64) * ld, dA + i * 4096);
    #pragma unroll
    for (int j2 = 0; j2 < 2; ++j2) glds16(gww + (long)(j2 * 64) * P.ldw, dW + j2 * 4096);
  };

  // fragment read offsets (elements), XOR-swizzled within the 64-elem row
  int aoff[4], woff[4];
  #pragma unroll
  for (int m = 0; m < 4; ++m) aoff[m] = (wm + m * 16 + fr) * 64;
  #pragma unroll
  for (int n = 0; n < 4; ++n) woff[n] = (wn + n * 16 + fr) * 64;
  const int swz = (fr & 7) << 3;
  const int kk0 = (0 + fk) ^ swz;
  const int kk1 = (32 + fk) ^ swz;

  f32x4 acc[4][4] = {};
  const int nt = P.nt;

  // prologue: depth-2 prefetch (12 loads in flight)
  stage(0, 0);
  stage(1, 1);

  for (int t = 0; t < nt; ++t) {
    // tile t ready (drain its 6; leave t+1's 6 in flight), then raw barrier
    if (t + 1 < nt) asm volatile("s_waitcnt vmcnt(6)\n\ts_barrier" ::: "memory");
    else            asm volatile("s_waitcnt vmcnt(0)\n\ts_barrier" ::: "memory");
    if (t + 2 < nt) stage(t + 2, (t + 2) % 3);

    const u16* Ab = lA + (t % 3) * 16384;
    const u16* Wb = lW + (t % 3) * 8192;
    bf16x8 af0[4], wf0[4], af1[4], wf1[4];
    #pragma unroll
    for (int m = 0; m < 4; ++m) af0[m] = *(const bf16x8*)&Ab[aoff[m] + kk0];
    #pragma unroll
    for (int n = 0; n < 4; ++n) wf0[n] = *(const bf16x8*)&Wb[woff[n] + kk0];
    #pragma unroll
    for (int m = 0; m < 4; ++m) af1[m] = *(const bf16x8*)&Ab[aoff[m] + kk1];
    #pragma unroll
    for (int n = 0; n < 4; ++n) wf1[n] = *(const bf16x8*)&Wb[woff[n] + kk1];

    __builtin_amdgcn_s_setprio(1);
    #pragma unroll
    for (int m = 0; m < 4; ++m)
      #pragma unroll
      for (int n = 0; n < 4; ++n)
        acc[m][n] = __builtin_amdgcn_mfma_f32_16x16x32_bf16(af0[m], wf0[n], acc[m][n], 0, 0, 0);
    #pragma unroll
    for (int m = 0; m < 4; ++m)
      #pragma unroll
      for (int n = 0; n < 4; ++n)
        acc[m][n] = __builtin_amdgcn_mfma_f32_16x16x32_bf16(af1[m], wf1[n], acc[m][n], 0, 0, 0);
    __builtin_amdgcn_s_setprio(0);
  }

  const int cr = (lane >> 4) * 4;
  const int jg = wn >> 6;   // 0 or 1

  if (P.mode == 0) {
    const int j = tn * 32 + jg * 16 + fr;
    const float bi = P.bsum[j], bf = P.bsum[512 + j];
    const float bg = P.bsum[1024 + j], bo = P.bsum[1536 + j];
    #pragma unroll
    for (int m = 0; m < 4; ++m) {
      const long rbase = row0 + wm + m * 16 + cr;
      #pragma unroll
      for (int r = 0; r < 4; ++r) {
        const long ri = rbase + r;
        float gi = acc[m][0][r] + bi;
        float gf = acc[m][1][r] + bf;
        float gg = acc[m][2][r] + bg;
        float go = acc[m][3][r] + bo;
        float cv = P.cbuf[ri * H_ + j];
        float cn = sigmoidf_(gf) * cv + sigmoidf_(gi) * tanhf_(gg);
        float hn = sigmoidf_(go) * tanhf_(cn);
        P.cbuf[ri * H_ + j] = cn;
        P.hdst[ri * P.hld + P.hoff + j] = f2bf(hn);
        if (P.hf32) P.hf32[ri * H_ + j] = hn;
      }
    }
  } else {
    #pragma unroll
    for (int pp = 0; pp < 2; ++pp) {
      const int j = tn * 64 + jg * 32 + pp * 16 + fr;
      const float bj = P.bsum[j];
      #pragma unroll
      for (int m = 0; m < 4; ++m) {
        const long rbase = row0 + wm + m * 16 + cr;
        #pragma unroll
        for (int r = 0; r < 4; ++r) {
          const long ri = rbase + r;
          float gv = sigmoidf_(acc[m][2 * pp][r] + bj);
          float h0 = bf2f(P.h0src[ri * (long)P.h0ld + j]);
          float x1 = gv * h0 + (1.f - gv) * acc[m][2 * pp + 1][r];
          P.hdst[ri * P.hld + P.hoff + j] = f2bf(x1);
        }
      }
    }
  }
}

extern "C" void kernel_launch(void* const* d_in, const int* in_sizes, int n_in,
                              void* d_out, int out_size, void* d_ws, size_t ws_size,
                              hipStream_t stream) {
  const float* pred   = (const float*)d_in[0];
  const int*   labels = (const int*)d_in[1];
  const float* emb    = (const float*)d_in[2];
  const float* Wih0   = (const float*)d_in[3];
  const float* Whh0   = (const float*)d_in[4];
  const float* bih0   = (const float*)d_in[5];
  const float* bhh0   = (const float*)d_in[6];
  const float* hwW0   = (const float*)d_in[7];
  const float* hwb0   = (const float*)d_in[8];
  const float* linW0  = (const float*)d_in[9];
  const float* Wih1   = (const float*)d_in[10];
  const float* Whh1   = (const float*)d_in[11];
  const float* bih1   = (const float*)d_in[12];
  const float* bhh1   = (const float*)d_in[13];
  float* out = (float*)d_out;

  char* ws = (char*)d_ws;
  size_t off = 0;
  auto alloc = [&](size_t bytes) {
    char* p = ws + off;
    off = (off + bytes + 255) & ~(size_t)255;
    return p;
  };
  u16* WC0   = (u16*)alloc((size_t)S_ * G4H * K0_ * 2);   // gate-ilv [Wp|Wh|We]
  u16* WHLw  = (u16*)alloc((size_t)S_ * 1024 * K0_ * 2);  // [hw16|lin16]
  u16* WC1   = (u16*)alloc((size_t)S_ * G4H * KX1 * 2);   // gate-ilv [Wih1|Whh1]
  u16* xcat  = (u16*)alloc((size_t)B_ * XW * 2);          // [pred|h0_a|h0_b]
  u16* EMB   = (u16*)alloc((size_t)S_ * B_ * E_ * 2);     // pre-gathered embeddings
  u16* x1cat = (u16*)alloc((size_t)B_ * X1W * 2);         // [x1_a|x1_b|h1_a|h1_b]
  float* c0   = (float*)alloc((size_t)B_ * H_ * 4);
  float* c1   = (float*)alloc((size_t)B_ * H_ * 4);
  float* bs0  = (float*)alloc((size_t)S_ * G4H * 4);
  float* bs1  = (float*)alloc((size_t)S_ * G4H * 4);

  auto mkPk = [&](int s) {
    PackP K;
    K.wih0 = Wih0 + (size_t)s * G4H * D0_;
    K.whh0 = Whh0 + (size_t)s * G4H * H_;
    K.wih1 = Wih1 + (size_t)s * G4H * H_;
    K.whh1 = Whh1 + (size_t)s * G4H * H_;
    K.hww  = hwW0 + (size_t)s * H_ * K0_;
    K.linw = linW0 + (size_t)s * H_ * D0_;
    K.wc0  = WC0  + (size_t)s * G4H * K0_;
    K.wc1  = WC1  + (size_t)s * G4H * KX1;
    K.whl  = WHLw + (size_t)s * 1024 * K0_;
    return K;
  };

  // -------- phase A: slot-0 pack (rider-only launch) + state init -------------
  GemmP z = {};
  gemm_multi<<<440, 512, 0, stream>>>(z, z, z, mkPk(0), 0, 0, 0);
  pack_predz4<<<1024, 256, 0, stream>>>(pred, xcat);
  xgather<<<B_, E_, 0, stream>>>(emb, labels, EMB);
  bias_sum<<<56, 256, 0, stream>>>(bih0, bhh0, bs0, S_ * G4H);
  bias_sum<<<56, 256, 0, stream>>>(bih1, bhh1, bs1, S_ * G4H);
  zero_f<<<256, 256, 0, stream>>>(c0, B_ * H_);
  zero_f<<<256, 256, 0, stream>>>(c1, B_ * H_);
  zero_u16k<<<2048, 256, 0, stream>>>(x1cat, B_ * X1W);

  // -------- role builders (M-tile 256, N-tile 128) ----------------------------
  auto mkA = [&](int s) {              // G0_s: [pred|h0_{s-1}|emb_s] @ WC0_s^T
    GemmP P;
    P.r0 = xcat;                               P.ld0 = XW;  P.t1 = 16;
    P.r1 = xcat + 1024 + ((s + 1) & 1) * 512;  P.ld1 = XW;  P.t2 = 24;
    P.r2 = EMB + (size_t)s * B_ * E_;          P.ld2 = E_;
    P.W = WC0 + (size_t)s * G4H * K0_;         P.ldw = K0_; P.nt = 26;
    P.ntn = 16; P.tnw_sh = 3; P.ncc_sh = 1; P.tmw = 4;      // 256 blocks
    P.bsum = bs0 + (size_t)s * G4H; P.cbuf = c0;
    P.hdst = xcat; P.hld = XW; P.hoff = 1024 + (s & 1) * 512;
    P.hf32 = nullptr; P.h0src = xcat; P.h0ld = 0; P.mode = 0;
    return P;
  };
  auto mkB = [&](int s) {              // WHL_s: [pred|h0_s|emb_s] @ WHL_s^T
    GemmP P;
    P.r0 = xcat;                               P.ld0 = XW;  P.t1 = 16;
    P.r1 = xcat + 1024 + (s & 1) * 512;        P.ld1 = XW;  P.t2 = 24;
    P.r2 = EMB + (size_t)s * B_ * E_;          P.ld2 = E_;
    P.W = WHLw + (size_t)s * 1024 * K0_;       P.ldw = K0_; P.nt = 26;
    P.ntn = 8; P.tnw_sh = 2; P.ncc_sh = 1; P.tmw = 4;       // 128 blocks
    P.bsum = hwb0 + (size_t)s * H_; P.cbuf = nullptr;
    P.hdst = x1cat; P.hld = X1W; P.hoff = (s & 1) * 512;
    P.hf32 = nullptr;
    P.h0src = xcat + 1024 + (s & 1) * 512; P.h0ld = XW; P.mode = 1;
    return P;
  };
  auto mkC = [&](int s) {              // G1_s: [x1_s|h1_{s-1}] @ WC1_s^T
    GemmP P;
    P.r0 = x1cat + (s & 1) * 512;              P.ld0 = X1W; P.t1 = 8;
    P.r1 = x1cat + 1024 + ((s + 1) & 1) * 512; P.ld1 = X1W; P.t2 = 16;
    P.r2 = P.r0;                               P.ld2 = X1W;
    P.W = WC1 + (size_t)s * G4H * KX1;         P.ldw = KX1; P.nt = 16;
    P.ntn = 16; P.tnw_sh = 3; P.ncc_sh = 1; P.tmw = 4;      // 256 blocks
    P.bsum = bs1 + (size_t)s * G4H; P.cbuf = c1;
    P.hdst = x1cat; P.hld = X1W; P.hoff = 1024 + (s & 1) * 512;
    P.hf32 = (s == 6) ? out : nullptr; P.h0src = x1cat; P.h0ld = 0; P.mode = 0;
    return P;
  };

  // -------- pipelined slot loop: L_k = { G0_k, WHL_{k-1}, G1_{k-2}, pack_{k+1} }
  for (int k = 0; k <= 8; ++k) {
    const int nA = (k <= 6) ? 256 : 0;
    const int nB = (k >= 1 && k <= 7) ? 128 : 0;
    const int nC = (k >= 2) ? 256 : 0;
    const int nD = (k <= 5) ? 440 : 0;
    GemmP pa, pb, pc;
    if (nA) pa = mkA(k);
    if (nB) pb = mkB(k - 1);
    if (nC) pc = mkC(k - 2);
    GemmP any = nA ? pa : (nB ? pb : pc);
    if (!nA) pa = any;
    if (!nB) pb = any;
    if (!nC) pc = any;
    PackP pk = mkPk(nD ? (k + 1) : 0);
    gemm_multi<<<nA + nB + nC + nD, 512, 0, stream>>>(pa, pb, pc, pk,
                                                      nA, nA + nB, nA + nB + nC);
  }
}